// Round 2
// baseline (2004.987 us; speedup 1.0000x reference)
//
#include <hip/hip_runtime.h>
#include <hip/hip_bf16.h>

// Problem constants (match reference)
constexpr int Bv  = 2;
constexpr int Sv  = 2048;
constexpr int Dv  = 1024;
constexpr int Hv  = 16;
constexpr int DKv = 64;
constexpr int NTOK = Bv * Sv;  // 4096

// ---------------------------------------------------------------------------
// GEMM (NT) body: Y[n,e] = sum_d A[n,d] * W[e,d]
//   A: [M,Dv] rowmajor, W: [Dv,Dv] rowmajor ("out,in" -> y = x @ W^T)
// MODE 0: scatter Y into [B,H,S,DK] layout (for attention)
// MODE 1: plain row-major [n, e] (final output)
// 128x128 tile, BK=16, 256 threads, 8x8 micro-tile (cols split 4+4 so LDS
// b128 fragment reads are <=2-way bank aliased = free on CDNA4 [m136]).
// ---------------------------------------------------------------------------
template <int MODE>
__device__ __forceinline__
void gemm_body(const float* __restrict__ A, const float* __restrict__ W,
               float* __restrict__ Y, int bm, int bn, int tid) {
  constexpr int BM = 128, BK = 16;
  __shared__ __align__(16) float As[BK][132];  // [k][row], 132: 2-way on store
  __shared__ __align__(16) float Bs[BK][132];  // [k][col]

  const int ty = tid >> 4;    // 0..15 -> 8 rows each
  const int tx = tid & 15;    // 0..15 -> cols tx*4 and 64+tx*4

  // staging: thread loads rows (tid>>2) and +64, k-offset (tid&3)*4
  const int sr = tid >> 2;          // 0..63
  const int sk = (tid & 3) << 2;    // 0,4,8,12
  const float* Ap = A + (size_t)(bm * BM + sr) * Dv + sk;
  const float* Wp = W + (size_t)(bn * BM + sr) * Dv + sk;

  float acc[8][8];
#pragma unroll
  for (int i = 0; i < 8; ++i)
#pragma unroll
    for (int j = 0; j < 8; ++j) acc[i][j] = 0.f;

  for (int kt = 0; kt < Dv / BK; ++kt) {
    const float4 a0 = *reinterpret_cast<const float4*>(Ap + kt * BK);
    const float4 a1 = *reinterpret_cast<const float4*>(Ap + (size_t)64 * Dv + kt * BK);
    const float4 b0 = *reinterpret_cast<const float4*>(Wp + kt * BK);
    const float4 b1 = *reinterpret_cast<const float4*>(Wp + (size_t)64 * Dv + kt * BK);
    __syncthreads();
    As[sk + 0][sr] = a0.x; As[sk + 1][sr] = a0.y; As[sk + 2][sr] = a0.z; As[sk + 3][sr] = a0.w;
    As[sk + 0][sr + 64] = a1.x; As[sk + 1][sr + 64] = a1.y; As[sk + 2][sr + 64] = a1.z; As[sk + 3][sr + 64] = a1.w;
    Bs[sk + 0][sr] = b0.x; Bs[sk + 1][sr] = b0.y; Bs[sk + 2][sr] = b0.z; Bs[sk + 3][sr] = b0.w;
    Bs[sk + 0][sr + 64] = b1.x; Bs[sk + 1][sr + 64] = b1.y; Bs[sk + 2][sr + 64] = b1.z; Bs[sk + 3][sr + 64] = b1.w;
    __syncthreads();

#pragma unroll
    for (int k = 0; k < BK; ++k) {
      float a[8], b[8];
      *reinterpret_cast<float4*>(&a[0]) = *reinterpret_cast<const float4*>(&As[k][ty * 8]);
      *reinterpret_cast<float4*>(&a[4]) = *reinterpret_cast<const float4*>(&As[k][ty * 8 + 4]);
      *reinterpret_cast<float4*>(&b[0]) = *reinterpret_cast<const float4*>(&Bs[k][tx * 4]);
      *reinterpret_cast<float4*>(&b[4]) = *reinterpret_cast<const float4*>(&Bs[k][64 + tx * 4]);
#pragma unroll
      for (int i = 0; i < 8; ++i)
#pragma unroll
        for (int j = 0; j < 8; ++j) acc[i][j] += a[i] * b[j];
    }
  }

  const int grow = bm * BM + ty * 8;
#pragma unroll
  for (int i = 0; i < 8; ++i) {
    const int n = grow + i;
#pragma unroll
    for (int half = 0; half < 2; ++half) {
      const int e = bn * BM + half * 64 + tx * 4;
      const float4 vv = make_float4(acc[i][half * 4 + 0], acc[i][half * 4 + 1],
                                    acc[i][half * 4 + 2], acc[i][half * 4 + 3]);
      if (MODE == 0) {
        const int bb = n >> 11, ss = n & (Sv - 1);
        const int hh = e >> 6, dk = e & (DKv - 1);
        *reinterpret_cast<float4*>(&Y[(((size_t)bb * Hv + hh) * Sv + ss) * DKv + dk]) = vv;
      } else {
        *reinterpret_cast<float4*>(&Y[(size_t)n * Dv + e]) = vv;
      }
    }
  }
}

// Fused Q/K/V projections: blockIdx.z selects which GEMM. 768 blocks total
// -> 2 blocks/CU co-resident (vs 1/CU for a single 256-block GEMM).
__global__ __launch_bounds__(256, 2)
void gemm_qkv(const float* __restrict__ q, const float* __restrict__ k,
              const float* __restrict__ v,
              const float* __restrict__ Wq, const float* __restrict__ Wk,
              const float* __restrict__ Wv,
              float* __restrict__ Qw, float* __restrict__ Kw,
              float* __restrict__ Vw) {
  const float* A;
  const float* W;
  float* Y;
  if (blockIdx.z == 0)      { A = q; W = Wq; Y = Qw; }
  else if (blockIdx.z == 1) { A = k; W = Wk; Y = Kw; }
  else                      { A = v; W = Wv; Y = Vw; }
  gemm_body<0>(A, W, Y, blockIdx.y, blockIdx.x, threadIdx.x);
}

// Final output projection.
__global__ __launch_bounds__(256, 2)
void gemm_out(const float* __restrict__ X, const float* __restrict__ Wo,
              float* __restrict__ out) {
  gemm_body<1>(X, Wo, out, blockIdx.y, blockIdx.x, threadIdx.x);
}

// ---------------------------------------------------------------------------
// Causal flash attention, fp32. One block = one (b,h) x 64 query rows.
// 4 waves x 16 rows. K/V tiles in LDS (pad 65 => 2-way/conflict-free reads).
// Scores: lane = key col, K row in regs, Q read as b128 broadcast.
// Softmax: 64-lane shfl_xor butterflies, online (m, l) state per row.
// PV: P staged via LDS (pad 68, b128 broadcast), lane = dk, V cols in regs.
// ---------------------------------------------------------------------------
__global__ __launch_bounds__(256, 2)
void attn_fwd(const float* __restrict__ Q, const float* __restrict__ K,
              const float* __restrict__ V, float* __restrict__ X) {
  const int tid = threadIdx.x;
  const int lane = tid & 63;
  const int wid = tid >> 6;      // 0..3
  const int qt = blockIdx.x;     // 0..31 query tile
  const int bh = blockIdx.y;     // 0..31
  const int b = bh >> 4, h = bh & (Hv - 1);

  const float* Qb = Q + (size_t)bh * Sv * DKv;
  const float* Kb = K + (size_t)bh * Sv * DKv;
  const float* Vb = V + (size_t)bh * Sv * DKv;

  __shared__ __align__(16) float Qs[64][68];  // 272B row stride: b128-aligned
  __shared__ __align__(16) float Ks[64][65];  // per-lane row reads, 2-way free
  __shared__ __align__(16) float Vs[64][65];  // per-lane col reads, 2-way free
  __shared__ __align__(16) float Ps[64][68];  // b128 broadcast reads

  // stage the Q tile once
#pragma unroll
  for (int l = 0; l < 4; ++l) {
    const int idx = l * 256 + tid;
    const int r = idx >> 4;
    const int f = (idx & 15) << 2;
    const float4 qv = *reinterpret_cast<const float4*>(Qb + (size_t)(qt * 64 + r) * DKv + f);
    Qs[r][f] = qv.x; Qs[r][f + 1] = qv.y; Qs[r][f + 2] = qv.z; Qs[r][f + 3] = qv.w;
  }

  float m[16], lsum[16], O[16];
#pragma unroll
  for (int i = 0; i < 16; ++i) { m[i] = -3.0e38f; lsum[i] = 0.f; O[i] = 0.f; }

  for (int kt = 0; kt <= qt; ++kt) {
    __syncthreads();  // also covers Qs staging on the first iteration
#pragma unroll
    for (int l = 0; l < 4; ++l) {
      const int idx = l * 256 + tid;
      const int r = idx >> 4;
      const int f = (idx & 15) << 2;
      const float4 kv = *reinterpret_cast<const float4*>(Kb + (size_t)(kt * 64 + r) * DKv + f);
      Ks[r][f] = kv.x; Ks[r][f + 1] = kv.y; Ks[r][f + 2] = kv.z; Ks[r][f + 3] = kv.w;
      const float4 vv = *reinterpret_cast<const float4*>(Vb + (size_t)(kt * 64 + r) * DKv + f);
      Vs[r][f] = vv.x; Vs[r][f + 1] = vv.y; Vs[r][f + 2] = vv.z; Vs[r][f + 3] = vv.w;
    }
    __syncthreads();

    // K fragment: lane holds K[kt*64+lane][0..63]
    float kreg[64];
#pragma unroll
    for (int d = 0; d < 64; ++d) kreg[d] = Ks[lane][d];

    const bool diag = (kt == qt);
#pragma unroll
    for (int rr = 0; rr < 16; ++rr) {
      const int wr = wid * 16 + rr;
      float s = 0.f;
#pragma unroll
      for (int d4 = 0; d4 < 16; ++d4) {
        const float4 qv = *reinterpret_cast<const float4*>(&Qs[wr][d4 << 2]);
        s += qv.x * kreg[d4 * 4 + 0];
        s += qv.y * kreg[d4 * 4 + 1];
        s += qv.z * kreg[d4 * 4 + 2];
        s += qv.w * kreg[d4 * 4 + 3];
      }
      s *= 0.125f;  // 1/sqrt(DK)
      if (diag && lane > wr) s = -3.0e38f;  // causal mask within diagonal tile
      // online softmax across the 64 key columns (one per lane)
      float mt = s;
#pragma unroll
      for (int off = 32; off; off >>= 1) mt = fmaxf(mt, __shfl_xor(mt, off));
      const float mnew = fmaxf(m[rr], mt);
      const float p = __expf(s - mnew);
      const float corr = __expf(m[rr] - mnew);
      float ps = p;
#pragma unroll
      for (int off = 32; off; off >>= 1) ps += __shfl_xor(ps, off);
      lsum[rr] = lsum[rr] * corr + ps;
      m[rr] = mnew;
      O[rr] *= corr;
      Ps[wr][lane] = p;  // wave-private rows: no cross-wave sync needed
    }

    // V fragment: lane holds V[kt*64+c][lane] for c=0..63
    float vreg[64];
#pragma unroll
    for (int c = 0; c < 64; ++c) vreg[c] = Vs[c][lane];

#pragma unroll
    for (int rr = 0; rr < 16; ++rr) {
      const int wr = wid * 16 + rr;
      float o = O[rr];
#pragma unroll
      for (int c4 = 0; c4 < 16; ++c4) {
        const float4 pv = *reinterpret_cast<const float4*>(&Ps[wr][c4 << 2]);
        o += pv.x * vreg[c4 * 4 + 0];
        o += pv.y * vreg[c4 * 4 + 1];
        o += pv.z * vreg[c4 * 4 + 2];
        o += pv.w * vreg[c4 * 4 + 3];
      }
      O[rr] = o;
    }
  }

  // epilogue: X[b, s, h*DK + dk] = O / lsum  (recombines heads)
#pragma unroll
  for (int rr = 0; rr < 16; ++rr) {
    const int wr = wid * 16 + rr;
    const int srow = qt * 64 + wr;
    X[((size_t)(b * Sv + srow)) * Dv + h * DKv + lane] = O[rr] / lsum[rr];
  }
}

// ---------------------------------------------------------------------------
// launch
// ---------------------------------------------------------------------------
extern "C" void kernel_launch(void* const* d_in, const int* in_sizes, int n_in,
                              void* d_out, int out_size, void* d_ws, size_t ws_size,
                              hipStream_t stream) {
  const float* q  = (const float*)d_in[0];
  const float* k  = (const float*)d_in[1];
  const float* v  = (const float*)d_in[2];
  // d_in[3] = mask: always causal tril -> handled analytically in attn_fwd
  const float* Wq = (const float*)d_in[4];
  const float* Wk = (const float*)d_in[5];
  const float* Wv = (const float*)d_in[6];
  const float* Wo = (const float*)d_in[7];
  float* out = (float*)d_out;

  // workspace: Q,K,V in [B,H,S,DK] + X in [B,S,D] = 4 x 16.78 MB
  constexpr size_t SEG = (size_t)Bv * Hv * Sv * DKv;  // 4194304 floats
  float* ws = (float*)d_ws;
  float* Qw = ws;
  float* Kw = ws + SEG;
  float* Vw = ws + 2 * SEG;
  float* Xw = ws + 3 * SEG;

  const dim3 blk(256);
  gemm_qkv<<<dim3(Dv / 128, NTOK / 128, 3), blk, 0, stream>>>(
      q, k, v, Wq, Wk, Wv, Qw, Kw, Vw);
  attn_fwd<<<dim3(Sv / 64, Bv * Hv), blk, 0, stream>>>(Qw, Kw, Vw, Xw);
  gemm_out<<<dim3(Dv / 128, NTOK / 128), blk, 0, stream>>>(Xw, Wo, out);
}

// Round 4
// 630.612 us; speedup vs baseline: 3.1794x; 3.1794x over previous
//
#include <hip/hip_runtime.h>

// Problem constants (match reference)
constexpr int Bv  = 2;
constexpr int Sv  = 2048;
constexpr int Dv  = 1024;
constexpr int Hv  = 16;
constexpr int DKv = 64;
constexpr int NTOK = Bv * Sv;  // 4096

// Q is pre-scaled at projection time by 1/sqrt(DK) * log2(e) so attention
// scores are already in exp2 domain: p = exp2(s - m) == exp(s_raw/8 - m_raw/8).
#define QSCALE 0.18033688011112042f  // 0.125 * 1.4426950408889634

typedef __attribute__((ext_vector_type(8))) short bf16x8;   // MFMA A/B frag (4 VGPR)
typedef __attribute__((ext_vector_type(4))) float f32x4;    // MFMA C/D frag

__device__ __forceinline__ ushort f2bf(float f) {
  // round-to-nearest-even fp32 -> bf16 (finite inputs only)
  unsigned int u = __float_as_uint(f);
  unsigned int r = (u + 0x7fffu + ((u >> 16) & 1u)) >> 16;
  return (ushort)r;
}

__device__ __forceinline__ float fast_exp2(float x) {
#if __has_builtin(__builtin_amdgcn_exp2f)
  return __builtin_amdgcn_exp2f(x);
#else
  return exp2f(x);
#endif
}

// XOR swizzle: permutes 16B blocks within a 128B row by row&7. Keeps b128
// reads 16B-aligned and spreads a column-read's 64 lanes uniformly over all
// 32 banks (T2 / Guideline 4).
__device__ __forceinline__ int swz(int byte_linear, int row) {
  return byte_linear ^ ((row & 7) << 4);
}

// ---------------------------------------------------------------------------
// GEMM (NT) body: Y[n,e] = sum_d A[n,d] * W[e,d]
// MODE 0: bf16 output scattered into [B,H,S,DK] (attention operand), *scale
// MODE 1: fp32 row-major [n,e] (final output)
// 128x128 tile, BK=16, 256 threads, 8x8 micro-tile.
// ---------------------------------------------------------------------------
template <int MODE>
__device__ __forceinline__
void gemm_body(const float* __restrict__ A, const float* __restrict__ W,
               void* __restrict__ Yv, int bm, int bn, int tid, float scale) {
  constexpr int BM = 128, BK = 16;
  __shared__ __align__(16) float As[BK][132];
  __shared__ __align__(16) float Bs[BK][132];

  const int ty = tid >> 4;
  const int tx = tid & 15;
  const int sr = tid >> 2;
  const int sk = (tid & 3) << 2;
  const float* Ap = A + (size_t)(bm * BM + sr) * Dv + sk;
  const float* Wp = W + (size_t)(bn * BM + sr) * Dv + sk;

  float acc[8][8];
#pragma unroll
  for (int i = 0; i < 8; ++i)
#pragma unroll
    for (int j = 0; j < 8; ++j) acc[i][j] = 0.f;

  for (int kt = 0; kt < Dv / BK; ++kt) {
    const float4 a0 = *reinterpret_cast<const float4*>(Ap + kt * BK);
    const float4 a1 = *reinterpret_cast<const float4*>(Ap + (size_t)64 * Dv + kt * BK);
    const float4 b0 = *reinterpret_cast<const float4*>(Wp + kt * BK);
    const float4 b1 = *reinterpret_cast<const float4*>(Wp + (size_t)64 * Dv + kt * BK);
    __syncthreads();
    As[sk + 0][sr] = a0.x; As[sk + 1][sr] = a0.y; As[sk + 2][sr] = a0.z; As[sk + 3][sr] = a0.w;
    As[sk + 0][sr + 64] = a1.x; As[sk + 1][sr + 64] = a1.y; As[sk + 2][sr + 64] = a1.z; As[sk + 3][sr + 64] = a1.w;
    Bs[sk + 0][sr] = b0.x; Bs[sk + 1][sr] = b0.y; Bs[sk + 2][sr] = b0.z; Bs[sk + 3][sr] = b0.w;
    Bs[sk + 0][sr + 64] = b1.x; Bs[sk + 1][sr + 64] = b1.y; Bs[sk + 2][sr + 64] = b1.z; Bs[sk + 3][sr + 64] = b1.w;
    __syncthreads();

#pragma unroll
    for (int k = 0; k < BK; ++k) {
      float a[8], b[8];
      *reinterpret_cast<float4*>(&a[0]) = *reinterpret_cast<const float4*>(&As[k][ty * 8]);
      *reinterpret_cast<float4*>(&a[4]) = *reinterpret_cast<const float4*>(&As[k][ty * 8 + 4]);
      *reinterpret_cast<float4*>(&b[0]) = *reinterpret_cast<const float4*>(&Bs[k][tx * 4]);
      *reinterpret_cast<float4*>(&b[4]) = *reinterpret_cast<const float4*>(&Bs[k][64 + tx * 4]);
#pragma unroll
      for (int i = 0; i < 8; ++i)
#pragma unroll
        for (int j = 0; j < 8; ++j) acc[i][j] += a[i] * b[j];
    }
  }

  const int grow = bm * BM + ty * 8;
#pragma unroll
  for (int i = 0; i < 8; ++i) {
    const int n = grow + i;
#pragma unroll
    for (int half = 0; half < 2; ++half) {
      const int e = bn * BM + half * 64 + tx * 4;
      if (MODE == 0) {
        // bf16 scatter into [B,H,S,DK]
        const int bb = n >> 11, ss = n & (Sv - 1);
        const int hh = e >> 6, dk = e & (DKv - 1);
        ushort4 us;
        us.x = f2bf(acc[i][half * 4 + 0] * scale);
        us.y = f2bf(acc[i][half * 4 + 1] * scale);
        us.z = f2bf(acc[i][half * 4 + 2] * scale);
        us.w = f2bf(acc[i][half * 4 + 3] * scale);
        ushort* Y = (ushort*)Yv;
        *reinterpret_cast<ushort4*>(&Y[(((size_t)bb * Hv + hh) * Sv + ss) * DKv + dk]) = us;
      } else {
        float* Y = (float*)Yv;
        const float4 vv = make_float4(acc[i][half * 4 + 0], acc[i][half * 4 + 1],
                                      acc[i][half * 4 + 2], acc[i][half * 4 + 3]);
        *reinterpret_cast<float4*>(&Y[(size_t)n * Dv + e]) = vv;
      }
    }
  }
}

// Fused Q/K/V projections: blockIdx.z selects the GEMM; Q gets QSCALE.
__global__ __launch_bounds__(256, 2)
void gemm_qkv(const float* __restrict__ q, const float* __restrict__ k,
              const float* __restrict__ v,
              const float* __restrict__ Wq, const float* __restrict__ Wk,
              const float* __restrict__ Wv,
              ushort* __restrict__ Qw, ushort* __restrict__ Kw,
              ushort* __restrict__ Vw) {
  const float* A;
  const float* W;
  ushort* Y;
  float scale = 1.0f;
  if (blockIdx.z == 0)      { A = q; W = Wq; Y = Qw; scale = QSCALE; }
  else if (blockIdx.z == 1) { A = k; W = Wk; Y = Kw; }
  else                      { A = v; W = Wv; Y = Vw; }
  gemm_body<0>(A, W, Y, blockIdx.y, blockIdx.x, threadIdx.x, scale);
}

__global__ __launch_bounds__(256, 2)
void gemm_out(const float* __restrict__ X, const float* __restrict__ Wo,
              float* __restrict__ out) {
  gemm_body<1>(X, Wo, out, blockIdx.y, blockIdx.x, threadIdx.x, 1.0f);
}

// ---------------------------------------------------------------------------
// Causal flash attention, bf16 MFMA (16x16x32), fp32 softmax.
// Block = (b,h) x 64 q-rows; 4 waves, wave w owns q-rows w*16..w*16+15.
// Swapped QK^T: S^T = mfma(A=K, B=Q) so lane (c = l&15) owns ONE q-row's
// scores (16 values: key = kt*16 + 4g + r). Softmax: 15 fmax + 2 shfl_xor.
// P -> wave-private LDS (bf16, swizzled) -> PV A-frags. V staged transposed +
// even/odd-row packed so PV B-frags are single b128 reads.
// All LDS rows are 128B pitch with byte ^= (row&7)<<4 swizzle: b128 reads stay
// 16B-aligned and each wave access loads all 32 banks uniformly (8 words/bank
// = the 1KB/wave floor; naive pitch-64 would hotspot 16 banks at 2x).
// ---------------------------------------------------------------------------
__global__ __launch_bounds__(256)
void attn_fwd_mfma(const ushort* __restrict__ Q, const ushort* __restrict__ K,
                   const ushort* __restrict__ V, float* __restrict__ X) {
  const int tid  = threadIdx.x;
  const int lane = tid & 63;
  const int w    = tid >> 6;        // wave 0..3
  const int c    = lane & 15;       // frag col (q for scores; dk for PV out)
  const int g    = lane >> 4;       // lane group 0..3
  // long blocks (high qt) first: better tail packing under ~4 blocks/CU
  const int qt = (int)gridDim.x - 1 - (int)blockIdx.x;
  const int bh = blockIdx.y;
  const int b = bh >> 4, h = bh & (Hv - 1);

  const ushort* Qb = Q + (size_t)bh * Sv * DKv;
  const ushort* Kb = K + (size_t)bh * Sv * DKv;
  const ushort* Vb = V + (size_t)bh * Sv * DKv;

  __shared__ __align__(16) ushort QsL[64 * 64];      // [r][d] bf16, swizzled
  __shared__ __align__(16) ushort KsL[64 * 64];      // [r][d] bf16, swizzled
  __shared__ __align__(16) unsigned int VtL[64 * 32]; // [dk][rowpair] packed, swizzled
  __shared__ __align__(16) ushort PsL[4][16 * 64];   // per-wave P[q][k] bf16, swizzled

  // ---- stage Q tile (once) ----
  {
    const int r  = tid >> 2;             // 0..63
    const int c0 = (tid & 3) << 4;       // bf16 col 0,16,32,48
    const ushort* src = Qb + (size_t)(qt * 64 + r) * DKv + c0;
    uint4 v0 = *reinterpret_cast<const uint4*>(src);
    uint4 v1 = *reinterpret_cast<const uint4*>(src + 8);
    char* dst = (char*)QsL;
    *reinterpret_cast<uint4*>(dst + swz(r * 128 + 2 * c0, r))      = v0;
    *reinterpret_cast<uint4*>(dst + swz(r * 128 + 2 * c0 + 16, r)) = v1;
  }
  __syncthreads();

  // ---- Q frags (B-operand), held in regs for the whole KV loop ----
  bf16x8 qf0, qf1;
  {
    const int qr = w * 16 + c;
    const char* base = (const char*)QsL;
    qf0 = *reinterpret_cast<const bf16x8*>(base + swz(qr * 128 + 16 * g, qr));      // d 8g..8g+7
    qf1 = *reinterpret_cast<const bf16x8*>(base + swz(qr * 128 + 64 + 16 * g, qr)); // d 32+8g..
  }

  f32x4 accO[4];
#pragma unroll
  for (int ds = 0; ds < 4; ++ds) accO[ds] = (f32x4){0.f, 0.f, 0.f, 0.f};
  float m = -3.0e38f, lsum = 0.f;

  for (int kv = 0; kv <= qt; ++kv) {
    __syncthreads();  // all waves done reading previous K/V tiles
    // ---- stage K tile (row-major bf16, swizzled) ----
    {
      const int r  = tid >> 2;
      const int c0 = (tid & 3) << 4;
      const ushort* src = Kb + (size_t)(kv * 64 + r) * DKv + c0;
      uint4 v0 = *reinterpret_cast<const uint4*>(src);
      uint4 v1 = *reinterpret_cast<const uint4*>(src + 8);
      char* dst = (char*)KsL;
      *reinterpret_cast<uint4*>(dst + swz(r * 128 + 2 * c0, r))      = v0;
      *reinterpret_cast<uint4*>(dst + swz(r * 128 + 2 * c0 + 16, r)) = v1;
    }
    // ---- stage V tile transposed + even/odd packed: VtL[dk][i] = (V[2i][dk], V[2i+1][dk]) ----
    {
      const int i  = tid & 31;            // row pair 0..31
      const int c0 = (tid >> 5) << 3;     // dk 0,8,..,56
      const ushort* src = Vb + (size_t)(kv * 64 + 2 * i) * DKv + c0;
      uint4 e = *reinterpret_cast<const uint4*>(src);        // even row, 8 bf16
      uint4 o = *reinterpret_cast<const uint4*>(src + DKv);  // odd row
      unsigned int ee[4] = {e.x, e.y, e.z, e.w};
      unsigned int oo[4] = {o.x, o.y, o.z, o.w};
      char* dst = (char*)VtL;
#pragma unroll
      for (int p = 0; p < 4; ++p) {
        unsigned int lo = (ee[p] & 0xffffu) | (oo[p] << 16);       // col c0+2p
        unsigned int hi = (ee[p] >> 16) | (oo[p] & 0xffff0000u);   // col c0+2p+1
        const int d0 = c0 + 2 * p;
        *reinterpret_cast<unsigned int*>(dst + swz(d0 * 128 + 4 * i, d0))           = lo;
        *reinterpret_cast<unsigned int*>(dst + swz((d0 + 1) * 128 + 4 * i, d0 + 1)) = hi;
      }
    }
    __syncthreads();

    // ---- QK^T (swapped): s[kt] = S^T subtile; lane owns q=c, key=kt*16+4g+r ----
    f32x4 s[4];
    const char* kbase = (const char*)KsL;
#pragma unroll
    for (int kt = 0; kt < 4; ++kt) {
      const int kr = kt * 16 + c;
      bf16x8 kf0 = *reinterpret_cast<const bf16x8*>(kbase + swz(kr * 128 + 16 * g, kr));
      bf16x8 kf1 = *reinterpret_cast<const bf16x8*>(kbase + swz(kr * 128 + 64 + 16 * g, kr));
      f32x4 z = (f32x4){0.f, 0.f, 0.f, 0.f};
      z = __builtin_amdgcn_mfma_f32_16x16x32_bf16(kf0, qf0, z, 0, 0, 0);
      s[kt] = __builtin_amdgcn_mfma_f32_16x16x32_bf16(kf1, qf1, z, 0, 0, 0);
    }

    // ---- causal mask (diagonal tile only; wave-uniform branch) ----
    if (kv == qt) {
      const int ql = w * 16 + c;
#pragma unroll
      for (int kt = 0; kt < 4; ++kt)
#pragma unroll
        for (int rr = 0; rr < 4; ++rr) {
          const int kl = kt * 16 + 4 * g + rr;
          if (kl > ql) s[kt][rr] = -3.0e38f;
        }
    }

    // ---- online softmax (exp2 domain; Q pre-scaled by 0.125*log2e) ----
    float tm = -3.0e38f;
#pragma unroll
    for (int kt = 0; kt < 4; ++kt)
#pragma unroll
      for (int rr = 0; rr < 4; ++rr) tm = fmaxf(tm, s[kt][rr]);
    tm = fmaxf(tm, __shfl_xor(tm, 16));
    tm = fmaxf(tm, __shfl_xor(tm, 32));
    const float mnew = fmaxf(m, tm);
    const float corr = fast_exp2(m - mnew);
    m = mnew;

    float psum = 0.f;
#pragma unroll
    for (int kt = 0; kt < 4; ++kt)
#pragma unroll
      for (int rr = 0; rr < 4; ++rr) {
        const float p = fast_exp2(s[kt][rr] - mnew);
        s[kt][rr] = p;
        psum += p;
      }
    psum += __shfl_xor(psum, 16);
    psum += __shfl_xor(psum, 32);
    lsum = lsum * corr + psum;

    // ---- P -> wave-private LDS (bf16, row=q=c, swizzled) ----
    char* pbase = (char*)&PsL[w][0];
#pragma unroll
    for (int kt = 0; kt < 4; ++kt) {
      unsigned int lo = (unsigned int)f2bf(s[kt][0]) | ((unsigned int)f2bf(s[kt][1]) << 16);
      unsigned int hi = (unsigned int)f2bf(s[kt][2]) | ((unsigned int)f2bf(s[kt][3]) << 16);
      const int k0 = kt * 16 + 4 * g;
      *reinterpret_cast<unsigned int*>(pbase + swz(c * 128 + 2 * k0, c))     = lo;
      *reinterpret_cast<unsigned int*>(pbase + swz(c * 128 + 2 * k0 + 4, c)) = hi;
    }

    // ---- rescale accO: acc reg r holds q = 4g + r; corr lives in lane q ----
    float corr4[4];
#pragma unroll
    for (int rr = 0; rr < 4; ++rr)
      corr4[rr] = __int_as_float(__builtin_amdgcn_ds_bpermute(
          (4 * g + rr) << 2, __float_as_int(corr)));
#pragma unroll
    for (int ds = 0; ds < 4; ++ds)
#pragma unroll
      for (int rr = 0; rr < 4; ++rr) accO[ds][rr] *= corr4[rr];

    // ---- PV: accO[ds] += P[q][k] * V[k][dk] ----
    const char* vbase = (const char*)VtL;
#pragma unroll
    for (int ks = 0; ks < 2; ++ks) {
      bf16x8 pf = *reinterpret_cast<const bf16x8*>(pbase + swz(c * 128 + ks * 64 + 16 * g, c));
#pragma unroll
      for (int ds = 0; ds < 4; ++ds) {
        const int dk = ds * 16 + c;
        bf16x8 vf = *reinterpret_cast<const bf16x8*>(vbase + swz(dk * 128 + ks * 64 + 16 * g, dk));
        accO[ds] = __builtin_amdgcn_mfma_f32_16x16x32_bf16(pf, vf, accO[ds], 0, 0, 0);
      }
    }
  }

  // ---- epilogue: X[b, s, h*64+dk] = accO / lsum ----
  const float inv = 1.0f / lsum;  // valid in lane's q = c; uniform across groups
  float inv4[4];
#pragma unroll
  for (int rr = 0; rr < 4; ++rr)
    inv4[rr] = __int_as_float(__builtin_amdgcn_ds_bpermute(
        (4 * g + rr) << 2, __float_as_int(inv)));

  const int q0 = qt * 64 + w * 16;
#pragma unroll
  for (int ds = 0; ds < 4; ++ds)
#pragma unroll
    for (int rr = 0; rr < 4; ++rr) {
      const int srow = q0 + 4 * g + rr;
      X[((size_t)(b * Sv + srow)) * Dv + h * DKv + ds * 16 + c] = accO[ds][rr] * inv4[rr];
    }
}

// ---------------------------------------------------------------------------
// launch
// ---------------------------------------------------------------------------
extern "C" void kernel_launch(void* const* d_in, const int* in_sizes, int n_in,
                              void* d_out, int out_size, void* d_ws, size_t ws_size,
                              hipStream_t stream) {
  const float* q  = (const float*)d_in[0];
  const float* k  = (const float*)d_in[1];
  const float* v  = (const float*)d_in[2];
  // d_in[3] = mask: causal tril, handled analytically
  const float* Wq = (const float*)d_in[4];
  const float* Wk = (const float*)d_in[5];
  const float* Wv = (const float*)d_in[6];
  const float* Wo = (const float*)d_in[7];
  float* out = (float*)d_out;

  // workspace: Qw/Kw/Vw bf16 [B,H,S,DK] (8.39 MB each), Xw fp32 [B,S,D] (16.8 MB)
  constexpr size_t SEG = (size_t)Bv * Hv * Sv * DKv;  // 4194304 elements
  char* ws = (char*)d_ws;
  ushort* Qw = (ushort*)ws;
  ushort* Kw = (ushort*)(ws + SEG * 2);
  ushort* Vw = (ushort*)(ws + SEG * 4);
  float*  Xw = (float*)(ws + SEG * 6);

  const dim3 blk(256);
  gemm_qkv<<<dim3(Dv / 128, NTOK / 128, 3), blk, 0, stream>>>(
      q, k, v, Wq, Wk, Wv, Qw, Kw, Vw);
  attn_fwd_mfma<<<dim3(Sv / 64, Bv * Hv), blk, 0, stream>>>(Qw, Kw, Vw, Xw);
  gemm_out<<<dim3(Dv / 128, NTOK / 128), blk, 0, stream>>>(Xw, Wo, out);
}

// Round 5
// 362.100 us; speedup vs baseline: 5.5371x; 1.7415x over previous
//
#include <hip/hip_runtime.h>

// Problem constants (match reference)
constexpr int Bv  = 2;
constexpr int Sv  = 2048;
constexpr int Dv  = 1024;
constexpr int Hv  = 16;
constexpr int DKv = 64;
constexpr int NTOK = Bv * Sv;  // 4096

// Q is pre-scaled at projection time by 1/sqrt(DK) * log2(e) so attention
// scores are already in exp2 domain.
#define QSCALE 0.18033688011112042f  // 0.125 * 1.4426950408889634

typedef __attribute__((ext_vector_type(8))) short bf16x8;   // MFMA A/B frag (4 VGPR)
typedef __attribute__((ext_vector_type(4))) float f32x4;    // MFMA C/D frag

__device__ __forceinline__ ushort f2bf(float f) {
  // round-to-nearest-even fp32 -> bf16 (finite inputs only)
  unsigned int u = __float_as_uint(f);
  unsigned int r = (u + 0x7fffu + ((u >> 16) & 1u)) >> 16;
  return (ushort)r;
}

__device__ __forceinline__ float fast_exp2(float x) {
#if __has_builtin(__builtin_amdgcn_exp2f)
  return __builtin_amdgcn_exp2f(x);
#else
  return exp2f(x);
#endif
}

// XOR swizzle: permutes 16B blocks by row&7. Keeps b128 reads 16B-aligned and
// spreads column-reads across banks (T2 / Guideline 4).
__device__ __forceinline__ int swz(int byte_linear, int row) {
  return byte_linear ^ ((row & 7) << 4);
}

// ---------------------------------------------------------------------------
// Split-precision precompute: fp32 x -> (hi, lo) bf16 pair arrays.
// Layout: per 8-element k-octet O: dst[O*16+0..7] = hi, dst[O*16+8..15] = lo.
// hi = truncate(x) (mantissa AND), lo = truncate(x - hi). x == hi+lo to 2^-16.
// One thread per octet: 32B read, 32B write, fully coalesced segments.
// ---------------------------------------------------------------------------
__device__ __forceinline__ void split_octet(const float* __restrict__ src,
                                            ushort* __restrict__ dst, int o) {
  const float4 f0 = *reinterpret_cast<const float4*>(src + (size_t)o * 8);
  const float4 f1 = *reinterpret_cast<const float4*>(src + (size_t)o * 8 + 4);
  float xs[8] = {f0.x, f0.y, f0.z, f0.w, f1.x, f1.y, f1.z, f1.w};
  unsigned int hp[4], lp[4];
#pragma unroll
  for (int j = 0; j < 4; ++j) {
    const unsigned int u0 = __float_as_uint(xs[2 * j]);
    const unsigned int u1 = __float_as_uint(xs[2 * j + 1]);
    const unsigned int h0 = u0 & 0xffff0000u;
    const unsigned int h1 = u1 & 0xffff0000u;
    hp[j] = (h0 >> 16) | h1;
    const float r0 = xs[2 * j] - __uint_as_float(h0);
    const float r1 = xs[2 * j + 1] - __uint_as_float(h1);
    lp[j] = (__float_as_uint(r0) >> 16) | (__float_as_uint(r1) & 0xffff0000u);
  }
  uint4* d = reinterpret_cast<uint4*>(dst + (size_t)o * 16);
  d[0] = make_uint4(hp[0], hp[1], hp[2], hp[3]);
  d[1] = make_uint4(lp[0], lp[1], lp[2], lp[3]);
}

// y = 0..2: activations q,k,v (NTOK*Dv/8 = 524288 octets)
// y = 3..6: weights Wq,Wk,Wv,Wo (Dv*Dv/8 = 131072 octets)
__global__ __launch_bounds__(256)
void split7(const float* __restrict__ s0, const float* __restrict__ s1,
            const float* __restrict__ s2, const float* __restrict__ s3,
            const float* __restrict__ s4, const float* __restrict__ s5,
            const float* __restrict__ s6,
            ushort* __restrict__ d0, ushort* __restrict__ d1,
            ushort* __restrict__ d2, ushort* __restrict__ d3,
            ushort* __restrict__ d4, ushort* __restrict__ d5,
            ushort* __restrict__ d6) {
  const float* src;
  ushort* dst;
  int n;
  switch (blockIdx.y) {
    case 0: src = s0; dst = d0; n = NTOK * Dv / 8; break;
    case 1: src = s1; dst = d1; n = NTOK * Dv / 8; break;
    case 2: src = s2; dst = d2; n = NTOK * Dv / 8; break;
    case 3: src = s3; dst = d3; n = Dv * Dv / 8; break;
    case 4: src = s4; dst = d4; n = Dv * Dv / 8; break;
    case 5: src = s5; dst = d5; n = Dv * Dv / 8; break;
    default: src = s6; dst = d6; n = Dv * Dv / 8; break;
  }
  const int o = blockIdx.x * 256 + threadIdx.x;
  if (o < n) split_octet(src, dst, o);
}

__global__ __launch_bounds__(256)
void split1(const float* __restrict__ src, ushort* __restrict__ dst) {
  const int o = blockIdx.x * 256 + threadIdx.x;
  if (o < NTOK * Dv / 8) split_octet(src, dst, o);
}

// ---------------------------------------------------------------------------
// Split-precision bf16 MFMA GEMM: Y[n,e] = sum_d A[n,d] * W[e,d]
// A,W given as split arrays [rows][2048] bf16 (hi|lo per octet).
// 128x128 tile, BK=64, 256 threads = 4 waves (2x2), 64x64 per wave,
// 4x4 fragments, 3 mfma per fragment-pair (hi*hi + lo*hi + hi*lo).
// LDS 2x32KB, row pitch 256B, XOR-swizzled both sides.
// MODE 0: bf16 scatter into [B,H,S,DK], *scale.  MODE 1: fp32 [n,e].
// ---------------------------------------------------------------------------
template <int MODE>
__device__ __forceinline__
void gemm_mfma_body(const ushort* __restrict__ Ag, const ushort* __restrict__ Wg,
                    void* __restrict__ Yv, int bm, int bn, float scale) {
  __shared__ __align__(16) ushort AT[128 * 128];  // 32KB: [row][256B swizzled]
  __shared__ __align__(16) ushort WT[128 * 128];  // 32KB

  const int tid  = threadIdx.x;
  const int lane = tid & 63;
  const int wid  = tid >> 6;
  const int wr = wid >> 1, wc = wid & 1;   // wave grid 2x2
  const int c = lane & 15, g = lane >> 4;  // frag col / k-group

  f32x4 acc[4][4];
#pragma unroll
  for (int m = 0; m < 4; ++m)
#pragma unroll
    for (int n = 0; n < 4; ++n) acc[m][n] = (f32x4){0.f, 0.f, 0.f, 0.f};

  // staging: thread owns (srow + 16*it, sslot) 16B units; swizzle bits depend
  // only on srow&7 (it*16 = 0 mod 8), so dst advances linearly by 4KB per it.
  const int srow  = tid >> 4;   // 0..15
  const int sslot = tid & 15;   // 0..15
  const size_t aBase = (size_t)(bm * 128 + srow) * 2048 + sslot * 8;
  const size_t wBase = (size_t)(bn * 128 + srow) * 2048 + sslot * 8;
  const int sb = srow * 256 + ((sslot * 16) ^ ((srow & 7) << 4));

  for (int kt = 0; kt < 16; ++kt) {
    __syncthreads();
#pragma unroll
    for (int it = 0; it < 8; ++it)
      *reinterpret_cast<uint4*>((char*)AT + it * 4096 + sb) =
          *reinterpret_cast<const uint4*>(Ag + aBase + (size_t)it * 32768 + kt * 128);
#pragma unroll
    for (int it = 0; it < 8; ++it)
      *reinterpret_cast<uint4*>((char*)WT + it * 4096 + sb) =
          *reinterpret_cast<const uint4*>(Wg + wBase + (size_t)it * 32768 + kt * 128);
    __syncthreads();

#pragma unroll
    for (int kk = 0; kk < 2; ++kk) {
      const int ob = (kk * 4 + g) * 32;  // octet byte base (hi at +0, lo at +16)
      bf16x8 bh[4], bl[4];
#pragma unroll
      for (int n = 0; n < 4; ++n) {
        const int row = wc * 64 + n * 16 + c;
        const char* p = (const char*)WT;
        bh[n] = *reinterpret_cast<const bf16x8*>(p + swz(row * 256 + ob, row));
        bl[n] = *reinterpret_cast<const bf16x8*>(p + swz(row * 256 + ob + 16, row));
      }
#pragma unroll
      for (int m = 0; m < 4; ++m) {
        const int row = wr * 64 + m * 16 + c;
        const char* p = (const char*)AT;
        const bf16x8 ah = *reinterpret_cast<const bf16x8*>(p + swz(row * 256 + ob, row));
        const bf16x8 al = *reinterpret_cast<const bf16x8*>(p + swz(row * 256 + ob + 16, row));
#pragma unroll
        for (int n = 0; n < 4; ++n) {
          acc[m][n] = __builtin_amdgcn_mfma_f32_16x16x32_bf16(ah, bh[n], acc[m][n], 0, 0, 0);
          acc[m][n] = __builtin_amdgcn_mfma_f32_16x16x32_bf16(al, bh[n], acc[m][n], 0, 0, 0);
          acc[m][n] = __builtin_amdgcn_mfma_f32_16x16x32_bf16(ah, bl[n], acc[m][n], 0, 0, 0);
        }
      }
    }
  }

  // epilogue: lane owns rows 4g+r, col c of each 16x16 tile (m89 C/D layout)
#pragma unroll
  for (int m = 0; m < 4; ++m)
#pragma unroll
    for (int n = 0; n < 4; ++n)
#pragma unroll
      for (int r = 0; r < 4; ++r) {
        const int tok = bm * 128 + wr * 64 + m * 16 + 4 * g + r;
        const int e   = bn * 128 + wc * 64 + n * 16 + c;
        const float y = acc[m][n][r];
        if (MODE == 0) {
          const int bb = tok >> 11, ss = tok & (Sv - 1);
          const int hh = e >> 6, dk = e & (DKv - 1);
          ((ushort*)Yv)[(((size_t)bb * Hv + hh) * Sv + ss) * DKv + dk] = f2bf(y * scale);
        } else {
          ((float*)Yv)[(size_t)tok * Dv + e] = y;
        }
      }
}

__global__ __launch_bounds__(256, 2)
void gemm_qkv_mfma(const ushort* __restrict__ qS, const ushort* __restrict__ kS,
                   const ushort* __restrict__ vS,
                   const ushort* __restrict__ WqS, const ushort* __restrict__ WkS,
                   const ushort* __restrict__ WvS,
                   ushort* __restrict__ Qw, ushort* __restrict__ Kw,
                   ushort* __restrict__ Vw) {
  const ushort* A;
  const ushort* W;
  ushort* Y;
  float scale = 1.0f;
  if (blockIdx.z == 0)      { A = qS; W = WqS; Y = Qw; scale = QSCALE; }
  else if (blockIdx.z == 1) { A = kS; W = WkS; Y = Kw; }
  else                      { A = vS; W = WvS; Y = Vw; }
  gemm_mfma_body<0>(A, W, Y, blockIdx.y, blockIdx.x, scale);
}

__global__ __launch_bounds__(256, 2)
void gemm_out_mfma(const ushort* __restrict__ XS, const ushort* __restrict__ WoS,
                   float* __restrict__ out) {
  gemm_mfma_body<1>(XS, WoS, out, blockIdx.y, blockIdx.x, 1.0f);
}

// ---------------------------------------------------------------------------
// Causal flash attention, bf16 MFMA (16x16x32), fp32 softmax. (unchanged,
// verified round 4: passed, absmax 0.0156)
// ---------------------------------------------------------------------------
__global__ __launch_bounds__(256)
void attn_fwd_mfma(const ushort* __restrict__ Q, const ushort* __restrict__ K,
                   const ushort* __restrict__ V, float* __restrict__ X) {
  const int tid  = threadIdx.x;
  const int lane = tid & 63;
  const int w    = tid >> 6;        // wave 0..3
  const int c    = lane & 15;       // frag col (q for scores; dk for PV out)
  const int g    = lane >> 4;       // lane group 0..3
  const int qt = (int)gridDim.x - 1 - (int)blockIdx.x;
  const int bh = blockIdx.y;
  const int b = bh >> 4, h = bh & (Hv - 1);

  const ushort* Qb = Q + (size_t)bh * Sv * DKv;
  const ushort* Kb = K + (size_t)bh * Sv * DKv;
  const ushort* Vb = V + (size_t)bh * Sv * DKv;

  __shared__ __align__(16) ushort QsL[64 * 64];
  __shared__ __align__(16) ushort KsL[64 * 64];
  __shared__ __align__(16) unsigned int VtL[64 * 32];
  __shared__ __align__(16) ushort PsL[4][16 * 64];

  // ---- stage Q tile (once) ----
  {
    const int r  = tid >> 2;
    const int c0 = (tid & 3) << 4;
    const ushort* src = Qb + (size_t)(qt * 64 + r) * DKv + c0;
    uint4 v0 = *reinterpret_cast<const uint4*>(src);
    uint4 v1 = *reinterpret_cast<const uint4*>(src + 8);
    char* dst = (char*)QsL;
    *reinterpret_cast<uint4*>(dst + swz(r * 128 + 2 * c0, r))      = v0;
    *reinterpret_cast<uint4*>(dst + swz(r * 128 + 2 * c0 + 16, r)) = v1;
  }
  __syncthreads();

  bf16x8 qf0, qf1;
  {
    const int qr = w * 16 + c;
    const char* base = (const char*)QsL;
    qf0 = *reinterpret_cast<const bf16x8*>(base + swz(qr * 128 + 16 * g, qr));
    qf1 = *reinterpret_cast<const bf16x8*>(base + swz(qr * 128 + 64 + 16 * g, qr));
  }

  f32x4 accO[4];
#pragma unroll
  for (int ds = 0; ds < 4; ++ds) accO[ds] = (f32x4){0.f, 0.f, 0.f, 0.f};
  float m = -3.0e38f, lsum = 0.f;

  for (int kv = 0; kv <= qt; ++kv) {
    __syncthreads();
    {
      const int r  = tid >> 2;
      const int c0 = (tid & 3) << 4;
      const ushort* src = Kb + (size_t)(kv * 64 + r) * DKv + c0;
      uint4 v0 = *reinterpret_cast<const uint4*>(src);
      uint4 v1 = *reinterpret_cast<const uint4*>(src + 8);
      char* dst = (char*)KsL;
      *reinterpret_cast<uint4*>(dst + swz(r * 128 + 2 * c0, r))      = v0;
      *reinterpret_cast<uint4*>(dst + swz(r * 128 + 2 * c0 + 16, r)) = v1;
    }
    {
      const int i  = tid & 31;
      const int c0 = (tid >> 5) << 3;
      const ushort* src = Vb + (size_t)(kv * 64 + 2 * i) * DKv + c0;
      uint4 e = *reinterpret_cast<const uint4*>(src);
      uint4 o = *reinterpret_cast<const uint4*>(src + DKv);
      unsigned int ee[4] = {e.x, e.y, e.z, e.w};
      unsigned int oo[4] = {o.x, o.y, o.z, o.w};
      char* dst = (char*)VtL;
#pragma unroll
      for (int p = 0; p < 4; ++p) {
        unsigned int lo = (ee[p] & 0xffffu) | (oo[p] << 16);
        unsigned int hi = (ee[p] >> 16) | (oo[p] & 0xffff0000u);
        const int d0 = c0 + 2 * p;
        *reinterpret_cast<unsigned int*>(dst + swz(d0 * 128 + 4 * i, d0))           = lo;
        *reinterpret_cast<unsigned int*>(dst + swz((d0 + 1) * 128 + 4 * i, d0 + 1)) = hi;
      }
    }
    __syncthreads();

    f32x4 s[4];
    const char* kbase = (const char*)KsL;
#pragma unroll
    for (int kt = 0; kt < 4; ++kt) {
      const int kr = kt * 16 + c;
      bf16x8 kf0 = *reinterpret_cast<const bf16x8*>(kbase + swz(kr * 128 + 16 * g, kr));
      bf16x8 kf1 = *reinterpret_cast<const bf16x8*>(kbase + swz(kr * 128 + 64 + 16 * g, kr));
      f32x4 z = (f32x4){0.f, 0.f, 0.f, 0.f};
      z = __builtin_amdgcn_mfma_f32_16x16x32_bf16(kf0, qf0, z, 0, 0, 0);
      s[kt] = __builtin_amdgcn_mfma_f32_16x16x32_bf16(kf1, qf1, z, 0, 0, 0);
    }

    if (kv == qt) {
      const int ql = w * 16 + c;
#pragma unroll
      for (int kt = 0; kt < 4; ++kt)
#pragma unroll
        for (int rr = 0; rr < 4; ++rr) {
          const int kl = kt * 16 + 4 * g + rr;
          if (kl > ql) s[kt][rr] = -3.0e38f;
        }
    }

    float tm = -3.0e38f;
#pragma unroll
    for (int kt = 0; kt < 4; ++kt)
#pragma unroll
      for (int rr = 0; rr < 4; ++rr) tm = fmaxf(tm, s[kt][rr]);
    tm = fmaxf(tm, __shfl_xor(tm, 16));
    tm = fmaxf(tm, __shfl_xor(tm, 32));
    const float mnew = fmaxf(m, tm);
    const float corr = fast_exp2(m - mnew);
    m = mnew;

    float psum = 0.f;
#pragma unroll
    for (int kt = 0; kt < 4; ++kt)
#pragma unroll
      for (int rr = 0; rr < 4; ++rr) {
        const float p = fast_exp2(s[kt][rr] - mnew);
        s[kt][rr] = p;
        psum += p;
      }
    psum += __shfl_xor(psum, 16);
    psum += __shfl_xor(psum, 32);
    lsum = lsum * corr + psum;

    char* pbase = (char*)&PsL[w][0];
#pragma unroll
    for (int kt = 0; kt < 4; ++kt) {
      unsigned int lo = (unsigned int)f2bf(s[kt][0]) | ((unsigned int)f2bf(s[kt][1]) << 16);
      unsigned int hi = (unsigned int)f2bf(s[kt][2]) | ((unsigned int)f2bf(s[kt][3]) << 16);
      const int k0 = kt * 16 + 4 * g;
      *reinterpret_cast<unsigned int*>(pbase + swz(c * 128 + 2 * k0, c))     = lo;
      *reinterpret_cast<unsigned int*>(pbase + swz(c * 128 + 2 * k0 + 4, c)) = hi;
    }

    float corr4[4];
#pragma unroll
    for (int rr = 0; rr < 4; ++rr)
      corr4[rr] = __int_as_float(__builtin_amdgcn_ds_bpermute(
          (4 * g + rr) << 2, __float_as_int(corr)));
#pragma unroll
    for (int ds = 0; ds < 4; ++ds)
#pragma unroll
      for (int rr = 0; rr < 4; ++rr) accO[ds][rr] *= corr4[rr];

    const char* vbase = (const char*)VtL;
#pragma unroll
    for (int ks = 0; ks < 2; ++ks) {
      bf16x8 pf = *reinterpret_cast<const bf16x8*>(pbase + swz(c * 128 + ks * 64 + 16 * g, c));
#pragma unroll
      for (int ds = 0; ds < 4; ++ds) {
        const int dk = ds * 16 + c;
        bf16x8 vf = *reinterpret_cast<const bf16x8*>(vbase + swz(dk * 128 + ks * 64 + 16 * g, dk));
        accO[ds] = __builtin_amdgcn_mfma_f32_16x16x32_bf16(pf, vf, accO[ds], 0, 0, 0);
      }
    }
  }

  const float inv = 1.0f / lsum;
  float inv4[4];
#pragma unroll
  for (int rr = 0; rr < 4; ++rr)
    inv4[rr] = __int_as_float(__builtin_amdgcn_ds_bpermute(
        (4 * g + rr) << 2, __float_as_int(inv)));

  const int q0 = qt * 64 + w * 16;
#pragma unroll
  for (int ds = 0; ds < 4; ++ds)
#pragma unroll
    for (int rr = 0; rr < 4; ++rr) {
      const int srow = q0 + 4 * g + rr;
      X[((size_t)(b * Sv + srow)) * Dv + h * DKv + ds * 16 + c] = accO[ds][rr] * inv4[rr];
    }
}

// ---------------------------------------------------------------------------
// launch
// ---------------------------------------------------------------------------
extern "C" void kernel_launch(void* const* d_in, const int* in_sizes, int n_in,
                              void* d_out, int out_size, void* d_ws, size_t ws_size,
                              hipStream_t stream) {
  const float* q  = (const float*)d_in[0];
  const float* k  = (const float*)d_in[1];
  const float* v  = (const float*)d_in[2];
  // d_in[3] = mask: causal tril, handled analytically
  const float* Wq = (const float*)d_in[4];
  const float* Wk = (const float*)d_in[5];
  const float* Wv = (const float*)d_in[6];
  const float* Wo = (const float*)d_in[7];
  float* out = (float*)d_out;

  // workspace layout (bytes)
  constexpr size_t SEG   = (size_t)NTOK * Dv;       // 4194304 elements
  constexpr size_t ACT_S = SEG * 2;                 // bf16 [B,H,S,DK]   8.39MB
  constexpr size_t X_S   = SEG * 4;                 // fp32 [B,S,D]     16.78MB
  constexpr size_t SPA_S = SEG * 4;                 // split act bf16x2 16.78MB
  constexpr size_t SPW_S = (size_t)Dv * Dv * 4;     // split W bf16x2    4.19MB

  char* ws = (char*)d_ws;
  ushort* Qw  = (ushort*)(ws);
  ushort* Kw  = (ushort*)(ws + ACT_S);
  ushort* Vw  = (ushort*)(ws + 2 * ACT_S);
  float*  Xw  = (float*) (ws + 3 * ACT_S);
  ushort* qS  = (ushort*)(ws + 3 * ACT_S + X_S);
  ushort* kS  = (ushort*)(ws + 3 * ACT_S + X_S + SPA_S);
  ushort* vS  = (ushort*)(ws + 3 * ACT_S + X_S + 2 * SPA_S);
  ushort* WqS = (ushort*)(ws + 3 * ACT_S + X_S + 3 * SPA_S);
  ushort* WkS = (ushort*)(ws + 3 * ACT_S + X_S + 3 * SPA_S + SPW_S);
  ushort* WvS = (ushort*)(ws + 3 * ACT_S + X_S + 3 * SPA_S + 2 * SPW_S);
  ushort* WoS = (ushort*)(ws + 3 * ACT_S + X_S + 3 * SPA_S + 3 * SPW_S);
  ushort* XS  = (ushort*)(ws + 3 * ACT_S + X_S + 3 * SPA_S + 4 * SPW_S);

  const dim3 blk(256);
  split7<<<dim3(NTOK * Dv / 8 / 256, 7), blk, 0, stream>>>(
      q, k, v, Wq, Wk, Wv, Wo, qS, kS, vS, WqS, WkS, WvS, WoS);
  gemm_qkv_mfma<<<dim3(Dv / 128, NTOK / 128, 3), blk, 0, stream>>>(
      qS, kS, vS, WqS, WkS, WvS, Qw, Kw, Vw);
  attn_fwd_mfma<<<dim3(Sv / 64, Bv * Hv), blk, 0, stream>>>(Qw, Kw, Vw, Xw);
  split1<<<dim3(NTOK * Dv / 8 / 256), blk, 0, stream>>>(Xw, XS);
  gemm_out_mfma<<<dim3(Dv / 128, NTOK / 128), blk, 0, stream>>>(XS, WoS, out);
}

// Round 6
// 333.653 us; speedup vs baseline: 6.0092x; 1.0853x over previous
//
#include <hip/hip_runtime.h>

// Problem constants (match reference)
constexpr int Bv  = 2;
constexpr int Sv  = 2048;
constexpr int Dv  = 1024;
constexpr int Hv  = 16;
constexpr int DKv = 64;
constexpr int NTOK = Bv * Sv;  // 4096

// Q is pre-scaled at projection time by 1/sqrt(DK) * log2(e) so attention
// scores are already in exp2 domain.
#define QSCALE 0.18033688011112042f  // 0.125 * 1.4426950408889634

typedef __attribute__((ext_vector_type(8))) short bf16x8;   // MFMA A/B frag (4 VGPR)
typedef __attribute__((ext_vector_type(4))) float f32x4;    // MFMA C/D frag

__device__ __forceinline__ ushort f2bf(float f) {
  // round-to-nearest-even fp32 -> bf16 (finite inputs only)
  unsigned int u = __float_as_uint(f);
  unsigned int r = (u + 0x7fffu + ((u >> 16) & 1u)) >> 16;
  return (ushort)r;
}

__device__ __forceinline__ float fast_exp2(float x) {
#if __has_builtin(__builtin_amdgcn_exp2f)
  return __builtin_amdgcn_exp2f(x);
#else
  return exp2f(x);
#endif
}

// XOR swizzle: permutes 16B blocks by row&7. Keeps b128 reads 16B-aligned and
// spreads column-reads across banks (T2 / Guideline 4).
__device__ __forceinline__ int swz(int byte_linear, int row) {
  return byte_linear ^ ((row & 7) << 4);
}

// ---------------------------------------------------------------------------
// Split-precision precompute: fp32 x -> (hi, lo) bf16 pair arrays.
// Layout: per 8-element k-octet O: dst[O*16+0..7] = hi, dst[O*16+8..15] = lo.
// ---------------------------------------------------------------------------
__device__ __forceinline__ void split_octet(const float* __restrict__ src,
                                            ushort* __restrict__ dst, int o) {
  const float4 f0 = *reinterpret_cast<const float4*>(src + (size_t)o * 8);
  const float4 f1 = *reinterpret_cast<const float4*>(src + (size_t)o * 8 + 4);
  float xs[8] = {f0.x, f0.y, f0.z, f0.w, f1.x, f1.y, f1.z, f1.w};
  unsigned int hp[4], lp[4];
#pragma unroll
  for (int j = 0; j < 4; ++j) {
    const unsigned int u0 = __float_as_uint(xs[2 * j]);
    const unsigned int u1 = __float_as_uint(xs[2 * j + 1]);
    const unsigned int h0 = u0 & 0xffff0000u;
    const unsigned int h1 = u1 & 0xffff0000u;
    hp[j] = (h0 >> 16) | h1;
    const float r0 = xs[2 * j] - __uint_as_float(h0);
    const float r1 = xs[2 * j + 1] - __uint_as_float(h1);
    lp[j] = (__float_as_uint(r0) >> 16) | (__float_as_uint(r1) & 0xffff0000u);
  }
  uint4* d = reinterpret_cast<uint4*>(dst + (size_t)o * 16);
  d[0] = make_uint4(hp[0], hp[1], hp[2], hp[3]);
  d[1] = make_uint4(lp[0], lp[1], lp[2], lp[3]);
}

__global__ __launch_bounds__(256)
void split7(const float* __restrict__ s0, const float* __restrict__ s1,
            const float* __restrict__ s2, const float* __restrict__ s3,
            const float* __restrict__ s4, const float* __restrict__ s5,
            const float* __restrict__ s6,
            ushort* __restrict__ d0, ushort* __restrict__ d1,
            ushort* __restrict__ d2, ushort* __restrict__ d3,
            ushort* __restrict__ d4, ushort* __restrict__ d5,
            ushort* __restrict__ d6) {
  const float* src;
  ushort* dst;
  int n;
  switch (blockIdx.y) {
    case 0: src = s0; dst = d0; n = NTOK * Dv / 8; break;
    case 1: src = s1; dst = d1; n = NTOK * Dv / 8; break;
    case 2: src = s2; dst = d2; n = NTOK * Dv / 8; break;
    case 3: src = s3; dst = d3; n = Dv * Dv / 8; break;
    case 4: src = s4; dst = d4; n = Dv * Dv / 8; break;
    case 5: src = s5; dst = d5; n = Dv * Dv / 8; break;
    default: src = s6; dst = d6; n = Dv * Dv / 8; break;
  }
  const int o = blockIdx.x * 256 + threadIdx.x;
  if (o < n) split_octet(src, dst, o);
}

__global__ __launch_bounds__(256)
void split1(const float* __restrict__ src, ushort* __restrict__ dst) {
  const int o = blockIdx.x * 256 + threadIdx.x;
  if (o < NTOK * Dv / 8) split_octet(src, dst, o);
}

// ---------------------------------------------------------------------------
// Split-precision bf16 MFMA GEMM (verified round 5: absmax == bf16-attn floor)
// ---------------------------------------------------------------------------
template <int MODE>
__device__ __forceinline__
void gemm_mfma_body(const ushort* __restrict__ Ag, const ushort* __restrict__ Wg,
                    void* __restrict__ Yv, int bm, int bn, float scale) {
  __shared__ __align__(16) ushort AT[128 * 128];
  __shared__ __align__(16) ushort WT[128 * 128];

  const int tid  = threadIdx.x;
  const int lane = tid & 63;
  const int wid  = tid >> 6;
  const int wr = wid >> 1, wc = wid & 1;
  const int c = lane & 15, g = lane >> 4;

  f32x4 acc[4][4];
#pragma unroll
  for (int m = 0; m < 4; ++m)
#pragma unroll
    for (int n = 0; n < 4; ++n) acc[m][n] = (f32x4){0.f, 0.f, 0.f, 0.f};

  const int srow  = tid >> 4;
  const int sslot = tid & 15;
  const size_t aBase = (size_t)(bm * 128 + srow) * 2048 + sslot * 8;
  const size_t wBase = (size_t)(bn * 128 + srow) * 2048 + sslot * 8;
  const int sb = srow * 256 + ((sslot * 16) ^ ((srow & 7) << 4));

  for (int kt = 0; kt < 16; ++kt) {
    __syncthreads();
#pragma unroll
    for (int it = 0; it < 8; ++it)
      *reinterpret_cast<uint4*>((char*)AT + it * 4096 + sb) =
          *reinterpret_cast<const uint4*>(Ag + aBase + (size_t)it * 32768 + kt * 128);
#pragma unroll
    for (int it = 0; it < 8; ++it)
      *reinterpret_cast<uint4*>((char*)WT + it * 4096 + sb) =
          *reinterpret_cast<const uint4*>(Wg + wBase + (size_t)it * 32768 + kt * 128);
    __syncthreads();

#pragma unroll
    for (int kk = 0; kk < 2; ++kk) {
      const int ob = (kk * 4 + g) * 32;
      bf16x8 bh[4], bl[4];
#pragma unroll
      for (int n = 0; n < 4; ++n) {
        const int row = wc * 64 + n * 16 + c;
        const char* p = (const char*)WT;
        bh[n] = *reinterpret_cast<const bf16x8*>(p + swz(row * 256 + ob, row));
        bl[n] = *reinterpret_cast<const bf16x8*>(p + swz(row * 256 + ob + 16, row));
      }
#pragma unroll
      for (int m = 0; m < 4; ++m) {
        const int row = wr * 64 + m * 16 + c;
        const char* p = (const char*)AT;
        const bf16x8 ah = *reinterpret_cast<const bf16x8*>(p + swz(row * 256 + ob, row));
        const bf16x8 al = *reinterpret_cast<const bf16x8*>(p + swz(row * 256 + ob + 16, row));
#pragma unroll
        for (int n = 0; n < 4; ++n) {
          acc[m][n] = __builtin_amdgcn_mfma_f32_16x16x32_bf16(ah, bh[n], acc[m][n], 0, 0, 0);
          acc[m][n] = __builtin_amdgcn_mfma_f32_16x16x32_bf16(al, bh[n], acc[m][n], 0, 0, 0);
          acc[m][n] = __builtin_amdgcn_mfma_f32_16x16x32_bf16(ah, bl[n], acc[m][n], 0, 0, 0);
        }
      }
    }
  }

#pragma unroll
  for (int m = 0; m < 4; ++m)
#pragma unroll
    for (int n = 0; n < 4; ++n)
#pragma unroll
      for (int r = 0; r < 4; ++r) {
        const int tok = bm * 128 + wr * 64 + m * 16 + 4 * g + r;
        const int e   = bn * 128 + wc * 64 + n * 16 + c;
        const float y = acc[m][n][r];
        if (MODE == 0) {
          const int bb = tok >> 11, ss = tok & (Sv - 1);
          const int hh = e >> 6, dk = e & (DKv - 1);
          ((ushort*)Yv)[(((size_t)bb * Hv + hh) * Sv + ss) * DKv + dk] = f2bf(y * scale);
        } else {
          ((float*)Yv)[(size_t)tok * Dv + e] = y;
        }
      }
}

__global__ __launch_bounds__(256, 2)
void gemm_qkv_mfma(const ushort* __restrict__ qS, const ushort* __restrict__ kS,
                   const ushort* __restrict__ vS,
                   const ushort* __restrict__ WqS, const ushort* __restrict__ WkS,
                   const ushort* __restrict__ WvS,
                   ushort* __restrict__ Qw, ushort* __restrict__ Kw,
                   ushort* __restrict__ Vw) {
  const ushort* A;
  const ushort* W;
  ushort* Y;
  float scale = 1.0f;
  if (blockIdx.z == 0)      { A = qS; W = WqS; Y = Qw; scale = QSCALE; }
  else if (blockIdx.z == 1) { A = kS; W = WkS; Y = Kw; }
  else                      { A = vS; W = WvS; Y = Vw; }
  gemm_mfma_body<0>(A, W, Y, blockIdx.y, blockIdx.x, scale);
}

__global__ __launch_bounds__(256, 2)
void gemm_out_mfma(const ushort* __restrict__ XS, const ushort* __restrict__ WoS,
                   float* __restrict__ out) {
  gemm_mfma_body<1>(XS, WoS, out, blockIdx.y, blockIdx.x, 1.0f);
}

// ---------------------------------------------------------------------------
// Causal flash attention, bf16 MFMA, double-buffered + reg-prefetch (T3/T14).
// Block = (b,h) x 128 q-rows; 4 waves x 32 rows (two 16-row sub-tiles m=0,1).
// KV tile = 64 keys. Per iter: ONE barrier; next tile's K/V global loads are
// issued before compute and written to the alternate LDS buffer after compute
// (race-free: the target buffer was last read before the PREVIOUS barrier).
// K-frags and V-frags are shared across the two q sub-tiles (2x MFMA per read).
// LDS 48KB: K dbuf 16K | V dbuf 16K | P 16K; Q overlays K dbuf transiently.
// Numerics identical to the round-4/5 verified kernel (same KV tile order).
// ---------------------------------------------------------------------------
__global__ __launch_bounds__(256)
void attn_fwd_mfma(const ushort* __restrict__ Q, const ushort* __restrict__ K,
                   const ushort* __restrict__ V, float* __restrict__ X) {
  const int tid  = threadIdx.x;
  const int lane = tid & 63;
  const int w    = tid >> 6;        // wave 0..3
  const int c    = lane & 15;
  const int g    = lane >> 4;
  const int qt = (int)gridDim.x - 1 - (int)blockIdx.x;  // long blocks first
  const int bh = blockIdx.y;
  const int b = bh >> 4, h = bh & (Hv - 1);
  const int qtk = 2 * qt + 1;       // last KV tile index

  const ushort* Qb = Q + (size_t)bh * Sv * DKv;
  const ushort* Kb = K + (size_t)bh * Sv * DKv;
  const ushort* Vb = V + (size_t)bh * Sv * DKv;

  __shared__ __align__(16) char lds[49152];
  // K buf i: lds + i*8192            ([64 r][128B] swizzled)
  // V buf i: lds + 16384 + i*8192    ([64 dk][128B] pair-packed, swizzled)
  // P wave:  lds + 32768 + w*4096    ([32 r][128B] swizzled)
  // Q tile overlays [0, 16384) during init only.

  // ---- stage Q (128 rows x 128B) into K-dbuf region ----
#pragma unroll
  for (int l = 0; l < 2; ++l) {
    const int r  = l * 64 + (tid >> 2);
    const int c0 = (tid & 3) << 4;
    const ushort* src = Qb + (size_t)(qt * 128 + r) * DKv + c0;
    uint4 v0 = *reinterpret_cast<const uint4*>(src);
    uint4 v1 = *reinterpret_cast<const uint4*>(src + 8);
    *reinterpret_cast<uint4*>(lds + swz(r * 128 + 2 * c0, r))      = v0;
    *reinterpret_cast<uint4*>(lds + swz(r * 128 + 2 * c0 + 16, r)) = v1;
  }
  __syncthreads();

  // ---- Q frags (B-operand) for both sub-tiles, kept in regs ----
  bf16x8 qf0[2], qf1[2];
#pragma unroll
  for (int m = 0; m < 2; ++m) {
    const int qr = w * 32 + m * 16 + c;
    qf0[m] = *reinterpret_cast<const bf16x8*>(lds + swz(qr * 128 + 16 * g, qr));
    qf1[m] = *reinterpret_cast<const bf16x8*>(lds + swz(qr * 128 + 64 + 16 * g, qr));
  }

  // staging address components
  const int kr_s  = tid >> 2;            // K row 0..63
  const int kc_s  = (tid & 3) << 4;      // K col (bf16) 0,16,32,48
  const int vi_s  = tid & 31;            // V row pair 0..31
  const int vc_s  = (tid >> 5) << 3;     // V dk col 0,8,..,56

  uint4 kA, kB, vA, vB;  // prefetch registers
  {
    const ushort* ks = Kb + (size_t)kr_s * DKv + kc_s;
    kA = *reinterpret_cast<const uint4*>(ks);
    kB = *reinterpret_cast<const uint4*>(ks + 8);
    const ushort* vs = Vb + (size_t)(2 * vi_s) * DKv + vc_s;
    vA = *reinterpret_cast<const uint4*>(vs);
    vB = *reinterpret_cast<const uint4*>(vs + DKv);
  }
  __syncthreads();  // all waves done reading Q region before K write

  // write tile 0 into buf 0
  {
    char* kd = lds;
    *reinterpret_cast<uint4*>(kd + swz(kr_s * 128 + 2 * kc_s, kr_s))      = kA;
    *reinterpret_cast<uint4*>(kd + swz(kr_s * 128 + 2 * kc_s + 16, kr_s)) = kB;
    char* vd = lds + 16384;
    unsigned int ee[4] = {vA.x, vA.y, vA.z, vA.w};
    unsigned int oo[4] = {vB.x, vB.y, vB.z, vB.w};
#pragma unroll
    for (int p = 0; p < 4; ++p) {
      unsigned int lo = (ee[p] & 0xffffu) | (oo[p] << 16);
      unsigned int hi = (ee[p] >> 16) | (oo[p] & 0xffff0000u);
      const int d0 = vc_s + 2 * p;
      *reinterpret_cast<unsigned int*>(vd + swz(d0 * 128 + 4 * vi_s, d0))           = lo;
      *reinterpret_cast<unsigned int*>(vd + swz((d0 + 1) * 128 + 4 * vi_s, d0 + 1)) = hi;
    }
  }
  __syncthreads();

  f32x4 accO[2][4];
#pragma unroll
  for (int m = 0; m < 2; ++m)
#pragma unroll
    for (int ds = 0; ds < 4; ++ds) accO[m][ds] = (f32x4){0.f, 0.f, 0.f, 0.f};
  float mS[2] = {-3.0e38f, -3.0e38f};
  float lS[2] = {0.f, 0.f};

  for (int kv = 0; kv <= qtk; ++kv) {
    const int cur = kv & 1;

    // ---- issue next tile's global loads (in flight during compute) ----
    if (kv < qtk) {
      const ushort* ks = Kb + (size_t)((kv + 1) * 64 + kr_s) * DKv + kc_s;
      kA = *reinterpret_cast<const uint4*>(ks);
      kB = *reinterpret_cast<const uint4*>(ks + 8);
      const ushort* vs = Vb + (size_t)((kv + 1) * 64 + 2 * vi_s) * DKv + vc_s;
      vA = *reinterpret_cast<const uint4*>(vs);
      vB = *reinterpret_cast<const uint4*>(vs + DKv);
    }

    const char* kbase = lds + cur * 8192;
    const char* vbase = lds + 16384 + cur * 8192;
    char* pbase = lds + 32768 + w * 4096;

    // ---- QK^T: K frags shared across the two q sub-tiles ----
    f32x4 s[2][4];
#pragma unroll
    for (int kt = 0; kt < 4; ++kt) {
      const int kr = kt * 16 + c;
      bf16x8 kf0 = *reinterpret_cast<const bf16x8*>(kbase + swz(kr * 128 + 16 * g, kr));
      bf16x8 kf1 = *reinterpret_cast<const bf16x8*>(kbase + swz(kr * 128 + 64 + 16 * g, kr));
#pragma unroll
      for (int m = 0; m < 2; ++m) {
        f32x4 z = (f32x4){0.f, 0.f, 0.f, 0.f};
        z = __builtin_amdgcn_mfma_f32_16x16x32_bf16(kf0, qf0[m], z, 0, 0, 0);
        s[m][kt] = __builtin_amdgcn_mfma_f32_16x16x32_bf16(kf1, qf1[m], z, 0, 0, 0);
      }
    }

    // ---- causal mask (only the last two KV tiles intersect the diagonal) ----
    if (kv >= 2 * qt) {
#pragma unroll
      for (int m = 0; m < 2; ++m) {
        const int ql = qt * 128 + w * 32 + m * 16 + c;
#pragma unroll
        for (int kt = 0; kt < 4; ++kt)
#pragma unroll
          for (int rr = 0; rr < 4; ++rr) {
            const int kl = kv * 64 + kt * 16 + 4 * g + rr;
            if (kl > ql) s[m][kt][rr] = -3.0e38f;
          }
      }
    }

    // ---- online softmax + P write + acc rescale, per sub-tile ----
    float corrM[2];
#pragma unroll
    for (int m = 0; m < 2; ++m) {
      float tm = -3.0e38f;
#pragma unroll
      for (int kt = 0; kt < 4; ++kt)
#pragma unroll
        for (int rr = 0; rr < 4; ++rr) tm = fmaxf(tm, s[m][kt][rr]);
      tm = fmaxf(tm, __shfl_xor(tm, 16));
      tm = fmaxf(tm, __shfl_xor(tm, 32));
      const float mnew = fmaxf(mS[m], tm);
      corrM[m] = fast_exp2(mS[m] - mnew);
      mS[m] = mnew;

      float psum = 0.f;
#pragma unroll
      for (int kt = 0; kt < 4; ++kt)
#pragma unroll
        for (int rr = 0; rr < 4; ++rr) {
          const float p = fast_exp2(s[m][kt][rr] - mnew);
          s[m][kt][rr] = p;
          psum += p;
        }
      psum += __shfl_xor(psum, 16);
      psum += __shfl_xor(psum, 32);
      lS[m] = lS[m] * corrM[m] + psum;

      const int pr = m * 16 + c;
#pragma unroll
      for (int kt = 0; kt < 4; ++kt) {
        unsigned int lo = (unsigned int)f2bf(s[m][kt][0]) | ((unsigned int)f2bf(s[m][kt][1]) << 16);
        unsigned int hi = (unsigned int)f2bf(s[m][kt][2]) | ((unsigned int)f2bf(s[m][kt][3]) << 16);
        const int k0 = kt * 16 + 4 * g;
        *reinterpret_cast<unsigned int*>(pbase + swz(pr * 128 + 2 * k0, pr))     = lo;
        *reinterpret_cast<unsigned int*>(pbase + swz(pr * 128 + 2 * k0 + 4, pr)) = hi;
      }

      float corr4[4];
#pragma unroll
      for (int rr = 0; rr < 4; ++rr)
        corr4[rr] = __int_as_float(__builtin_amdgcn_ds_bpermute(
            (4 * g + rr) << 2, __float_as_int(corrM[m])));
#pragma unroll
      for (int ds = 0; ds < 4; ++ds)
#pragma unroll
        for (int rr = 0; rr < 4; ++rr) accO[m][ds][rr] *= corr4[rr];
    }

    // ---- PV: V frags shared across sub-tiles ----
#pragma unroll
    for (int ks = 0; ks < 2; ++ks) {
      bf16x8 vf[4];
#pragma unroll
      for (int ds = 0; ds < 4; ++ds) {
        const int dk = ds * 16 + c;
        vf[ds] = *reinterpret_cast<const bf16x8*>(vbase + swz(dk * 128 + ks * 64 + 16 * g, dk));
      }
#pragma unroll
      for (int m = 0; m < 2; ++m) {
        const int pr = m * 16 + c;
        bf16x8 pf = *reinterpret_cast<const bf16x8*>(pbase + swz(pr * 128 + ks * 64 + 16 * g, pr));
#pragma unroll
        for (int ds = 0; ds < 4; ++ds)
          accO[m][ds] = __builtin_amdgcn_mfma_f32_16x16x32_bf16(pf, vf[ds], accO[m][ds], 0, 0, 0);
      }
    }

    // ---- write next tile into alternate buffer (safe: last read 2 barriers ago) ----
    if (kv < qtk) {
      char* kd = lds + (cur ^ 1) * 8192;
      *reinterpret_cast<uint4*>(kd + swz(kr_s * 128 + 2 * kc_s, kr_s))      = kA;
      *reinterpret_cast<uint4*>(kd + swz(kr_s * 128 + 2 * kc_s + 16, kr_s)) = kB;
      char* vd = lds + 16384 + (cur ^ 1) * 8192;
      unsigned int ee[4] = {vA.x, vA.y, vA.z, vA.w};
      unsigned int oo[4] = {vB.x, vB.y, vB.z, vB.w};
#pragma unroll
      for (int p = 0; p < 4; ++p) {
        unsigned int lo = (ee[p] & 0xffffu) | (oo[p] << 16);
        unsigned int hi = (ee[p] >> 16) | (oo[p] & 0xffff0000u);
        const int d0 = vc_s + 2 * p;
        *reinterpret_cast<unsigned int*>(vd + swz(d0 * 128 + 4 * vi_s, d0))           = lo;
        *reinterpret_cast<unsigned int*>(vd + swz((d0 + 1) * 128 + 4 * vi_s, d0 + 1)) = hi;
      }
    }
    __syncthreads();
  }

  // ---- epilogue ----
#pragma unroll
  for (int m = 0; m < 2; ++m) {
    const float inv = 1.0f / lS[m];
    float inv4[4];
#pragma unroll
    for (int rr = 0; rr < 4; ++rr)
      inv4[rr] = __int_as_float(__builtin_amdgcn_ds_bpermute(
          (4 * g + rr) << 2, __float_as_int(inv)));
    const int q0 = qt * 128 + w * 32 + m * 16;
#pragma unroll
    for (int ds = 0; ds < 4; ++ds)
#pragma unroll
      for (int rr = 0; rr < 4; ++rr) {
        const int srow = q0 + 4 * g + rr;
        X[((size_t)(b * Sv + srow)) * Dv + h * DKv + ds * 16 + c] = accO[m][ds][rr] * inv4[rr];
      }
  }
}

// ---------------------------------------------------------------------------
// launch
// ---------------------------------------------------------------------------
extern "C" void kernel_launch(void* const* d_in, const int* in_sizes, int n_in,
                              void* d_out, int out_size, void* d_ws, size_t ws_size,
                              hipStream_t stream) {
  const float* q  = (const float*)d_in[0];
  const float* k  = (const float*)d_in[1];
  const float* v  = (const float*)d_in[2];
  // d_in[3] = mask: causal tril, handled analytically
  const float* Wq = (const float*)d_in[4];
  const float* Wk = (const float*)d_in[5];
  const float* Wv = (const float*)d_in[6];
  const float* Wo = (const float*)d_in[7];
  float* out = (float*)d_out;

  constexpr size_t SEG   = (size_t)NTOK * Dv;
  constexpr size_t ACT_S = SEG * 2;
  constexpr size_t X_S   = SEG * 4;
  constexpr size_t SPA_S = SEG * 4;
  constexpr size_t SPW_S = (size_t)Dv * Dv * 4;

  char* ws = (char*)d_ws;
  ushort* Qw  = (ushort*)(ws);
  ushort* Kw  = (ushort*)(ws + ACT_S);
  ushort* Vw  = (ushort*)(ws + 2 * ACT_S);
  float*  Xw  = (float*) (ws + 3 * ACT_S);
  ushort* qS  = (ushort*)(ws + 3 * ACT_S + X_S);
  ushort* kS  = (ushort*)(ws + 3 * ACT_S + X_S + SPA_S);
  ushort* vS  = (ushort*)(ws + 3 * ACT_S + X_S + 2 * SPA_S);
  ushort* WqS = (ushort*)(ws + 3 * ACT_S + X_S + 3 * SPA_S);
  ushort* WkS = (ushort*)(ws + 3 * ACT_S + X_S + 3 * SPA_S + SPW_S);
  ushort* WvS = (ushort*)(ws + 3 * ACT_S + X_S + 3 * SPA_S + 2 * SPW_S);
  ushort* WoS = (ushort*)(ws + 3 * ACT_S + X_S + 3 * SPA_S + 3 * SPW_S);
  ushort* XS  = (ushort*)(ws + 3 * ACT_S + X_S + 3 * SPA_S + 4 * SPW_S);

  const dim3 blk(256);
  split7<<<dim3(NTOK * Dv / 8 / 256, 7), blk, 0, stream>>>(
      q, k, v, Wq, Wk, Wv, Wo, qS, kS, vS, WqS, WkS, WvS, WoS);
  gemm_qkv_mfma<<<dim3(Dv / 128, NTOK / 128, 3), blk, 0, stream>>>(
      qS, kS, vS, WqS, WkS, WvS, Qw, Kw, Vw);
  attn_fwd_mfma<<<dim3(Sv / 128, Bv * Hv), blk, 0, stream>>>(Qw, Kw, Vw, Xw);
  split1<<<dim3(NTOK * Dv / 8 / 256), blk, 0, stream>>>(Xw, XS);
  gemm_out_mfma<<<dim3(Dv / 128, NTOK / 128), blk, 0, stream>>>(XS, WoS, out);
}

// Round 7
// 275.513 us; speedup vs baseline: 7.2773x; 1.2110x over previous
//
#include <hip/hip_runtime.h>

// Problem constants (match reference)
constexpr int Bv  = 2;
constexpr int Sv  = 2048;
constexpr int Dv  = 1024;
constexpr int Hv  = 16;
constexpr int DKv = 64;
constexpr int NTOK = Bv * Sv;  // 4096

// Q is pre-scaled at projection time by 1/sqrt(DK) * log2(e) so attention
// scores are already in exp2 domain.
#define QSCALE 0.18033688011112042f  // 0.125 * 1.4426950408889634

typedef __attribute__((ext_vector_type(8))) short bf16x8;   // MFMA A/B frag (4 VGPR)
typedef __attribute__((ext_vector_type(4))) float f32x4;    // MFMA C/D frag

__device__ __forceinline__ ushort f2bf(float f) {
  // round-to-nearest-even fp32 -> bf16 (finite inputs only)
  unsigned int u = __float_as_uint(f);
  unsigned int r = (u + 0x7fffu + ((u >> 16) & 1u)) >> 16;
  return (ushort)r;
}

__device__ __forceinline__ float fast_exp2(float x) {
#if __has_builtin(__builtin_amdgcn_exp2f)
  return __builtin_amdgcn_exp2f(x);
#else
  return exp2f(x);
#endif
}

// XOR swizzle: permutes 16B blocks by row&7 (T2 / Guideline 4).
__device__ __forceinline__ int swz(int byte_linear, int row) {
  return byte_linear ^ ((row & 7) << 4);
}

// ---------------------------------------------------------------------------
// Precompute pass: casts (f32 -> bf16) and the Wo split.
// cast_octet: 8 f32 -> 8 bf16 (32B read, 16B write).
// split_octet: 8 f32 -> [8 hi | 8 lo] bf16 (for the 3-term output GEMM).
// ---------------------------------------------------------------------------
__device__ __forceinline__ void cast_octet(const float* __restrict__ src,
                                           ushort* __restrict__ dst, int o) {
  const float4 f0 = *reinterpret_cast<const float4*>(src + (size_t)o * 8);
  const float4 f1 = *reinterpret_cast<const float4*>(src + (size_t)o * 8 + 4);
  uint4 u;
  u.x = (unsigned int)f2bf(f0.x) | ((unsigned int)f2bf(f0.y) << 16);
  u.y = (unsigned int)f2bf(f0.z) | ((unsigned int)f2bf(f0.w) << 16);
  u.z = (unsigned int)f2bf(f1.x) | ((unsigned int)f2bf(f1.y) << 16);
  u.w = (unsigned int)f2bf(f1.z) | ((unsigned int)f2bf(f1.w) << 16);
  *reinterpret_cast<uint4*>(dst + (size_t)o * 8) = u;
}

__device__ __forceinline__ void split_octet(const float* __restrict__ src,
                                            ushort* __restrict__ dst, int o) {
  const float4 f0 = *reinterpret_cast<const float4*>(src + (size_t)o * 8);
  const float4 f1 = *reinterpret_cast<const float4*>(src + (size_t)o * 8 + 4);
  float xs[8] = {f0.x, f0.y, f0.z, f0.w, f1.x, f1.y, f1.z, f1.w};
  unsigned int hp[4], lp[4];
#pragma unroll
  for (int j = 0; j < 4; ++j) {
    const unsigned int u0 = __float_as_uint(xs[2 * j]);
    const unsigned int u1 = __float_as_uint(xs[2 * j + 1]);
    const unsigned int h0 = u0 & 0xffff0000u;
    const unsigned int h1 = u1 & 0xffff0000u;
    hp[j] = (h0 >> 16) | h1;
    const float r0 = xs[2 * j] - __uint_as_float(h0);
    const float r1 = xs[2 * j + 1] - __uint_as_float(h1);
    lp[j] = (__float_as_uint(r0) >> 16) | (__float_as_uint(r1) & 0xffff0000u);
  }
  uint4* d = reinterpret_cast<uint4*>(dst + (size_t)o * 16);
  d[0] = make_uint4(hp[0], hp[1], hp[2], hp[3]);
  d[1] = make_uint4(lp[0], lp[1], lp[2], lp[3]);
}

// y = 0..2: cast q,k,v (524288 octets); y = 3..5: cast Wq,Wk,Wv (131072);
// y = 6: split Wo (131072 octets).
__global__ __launch_bounds__(256)
void cast_split(const float* __restrict__ q, const float* __restrict__ k,
                const float* __restrict__ v, const float* __restrict__ Wq,
                const float* __restrict__ Wk, const float* __restrict__ Wv,
                const float* __restrict__ Wo,
                ushort* __restrict__ qB, ushort* __restrict__ kB,
                ushort* __restrict__ vB, ushort* __restrict__ WqB,
                ushort* __restrict__ WkB, ushort* __restrict__ WvB,
                ushort* __restrict__ WoS) {
  const int o = blockIdx.x * 256 + threadIdx.x;
  constexpr int NA = NTOK * Dv / 8;  // 524288
  constexpr int NW = Dv * Dv / 8;    // 131072
  switch (blockIdx.y) {
    case 0: if (o < NA) cast_octet(q, qB, o); break;
    case 1: if (o < NA) cast_octet(k, kB, o); break;
    case 2: if (o < NA) cast_octet(v, vB, o); break;
    case 3: if (o < NW) cast_octet(Wq, WqB, o); break;
    case 4: if (o < NW) cast_octet(Wk, WkB, o); break;
    case 5: if (o < NW) cast_octet(Wv, WvB, o); break;
    default: if (o < NW) split_octet(Wo, WoS, o); break;
  }
}

__global__ __launch_bounds__(256)
void split1(const float* __restrict__ src, ushort* __restrict__ dst) {
  const int o = blockIdx.x * 256 + threadIdx.x;
  if (o < NTOK * Dv / 8) split_octet(src, dst, o);
}

// ---------------------------------------------------------------------------
// Plain bf16 MFMA GEMM for Q/K/V projections (error-neutral: outputs are
// bf16-rounded anyway; bf16-GEMM noise 1.6e-3 < output rounding noise 2.3e-3).
// Y[n,e] = sum_d A[n,d]*W[e,d]; A [NTOK][1024] bf16, W [1024][1024] bf16.
// 128x128 tile, BK=128, 4 waves (2x2), 4x4 frags. LDS 2x32KB, swizzled.
// XCD-aware block swizzle (T1): blocks sharing an A-slab are XCD-contiguous.
// ---------------------------------------------------------------------------
__global__ __launch_bounds__(256, 2)
void gemm_qkv_bf16(const ushort* __restrict__ qB, const ushort* __restrict__ kB,
                   const ushort* __restrict__ vB,
                   const ushort* __restrict__ WqB, const ushort* __restrict__ WkB,
                   const ushort* __restrict__ WvB,
                   ushort* __restrict__ Qw, ushort* __restrict__ Kw,
                   ushort* __restrict__ Vw) {
  // bijective XCD swizzle: nwg = 8*32*3 = 768 = 8*96
  const int hid = (int)blockIdx.z * 256 + (int)blockIdx.y * 8 + (int)blockIdx.x;
  const int id  = (hid & 7) * 96 + (hid >> 3);
  const int bn = id & 7;          // col tile
  const int bm = (id >> 3) & 31;  // row tile
  const int bz = id >> 8;         // which GEMM

  const ushort* Ag;
  const ushort* Wg;
  ushort* Y;
  float scale = 1.0f;
  if (bz == 0)      { Ag = qB; Wg = WqB; Y = Qw; scale = QSCALE; }
  else if (bz == 1) { Ag = kB; Wg = WkB; Y = Kw; }
  else              { Ag = vB; Wg = WvB; Y = Vw; }

  __shared__ __align__(16) ushort AT[128 * 128];  // 32KB, row pitch 256B, swz
  __shared__ __align__(16) ushort WT[128 * 128];  // 32KB

  const int tid  = threadIdx.x;
  const int lane = tid & 63;
  const int wid  = tid >> 6;
  const int wr = wid >> 1, wc = wid & 1;
  const int c = lane & 15, g = lane >> 4;

  f32x4 acc[4][4];
#pragma unroll
  for (int m = 0; m < 4; ++m)
#pragma unroll
    for (int n = 0; n < 4; ++n) acc[m][n] = (f32x4){0.f, 0.f, 0.f, 0.f};

  const int srow  = tid >> 4;   // 0..15
  const int sslot = tid & 15;   // 0..15
  const size_t aBase = (size_t)(bm * 128 + srow) * 1024 + sslot * 8;
  const size_t wBase = (size_t)(bn * 128 + srow) * 1024 + sslot * 8;
  const int sb = srow * 256 + ((sslot * 16) ^ ((srow & 7) << 4));

  for (int kt = 0; kt < 8; ++kt) {  // BK = 128
    __syncthreads();
#pragma unroll
    for (int it = 0; it < 8; ++it)
      *reinterpret_cast<uint4*>((char*)AT + it * 4096 + sb) =
          *reinterpret_cast<const uint4*>(Ag + aBase + (size_t)it * 16384 + kt * 128);
#pragma unroll
    for (int it = 0; it < 8; ++it)
      *reinterpret_cast<uint4*>((char*)WT + it * 4096 + sb) =
          *reinterpret_cast<const uint4*>(Wg + wBase + (size_t)it * 16384 + kt * 128);
    __syncthreads();

#pragma unroll
    for (int kk = 0; kk < 4; ++kk) {  // K = 32 per kk
      const int ob = kk * 64 + 16 * g;
      bf16x8 bh[4];
#pragma unroll
      for (int n = 0; n < 4; ++n) {
        const int row = wc * 64 + n * 16 + c;
        bh[n] = *reinterpret_cast<const bf16x8*>((const char*)WT + swz(row * 256 + ob, row));
      }
#pragma unroll
      for (int m = 0; m < 4; ++m) {
        const int row = wr * 64 + m * 16 + c;
        const bf16x8 ah = *reinterpret_cast<const bf16x8*>((const char*)AT + swz(row * 256 + ob, row));
#pragma unroll
        for (int n = 0; n < 4; ++n)
          acc[m][n] = __builtin_amdgcn_mfma_f32_16x16x32_bf16(ah, bh[n], acc[m][n], 0, 0, 0);
      }
    }
  }

  // epilogue: bf16 scatter into [B,H,S,DK], *scale
#pragma unroll
  for (int m = 0; m < 4; ++m)
#pragma unroll
    for (int n = 0; n < 4; ++n)
#pragma unroll
      for (int r = 0; r < 4; ++r) {
        const int tok = bm * 128 + wr * 64 + m * 16 + 4 * g + r;
        const int e   = bn * 128 + wc * 64 + n * 16 + c;
        const int bb = tok >> 11, ss = tok & (Sv - 1);
        const int hh = e >> 6, dk = e & (DKv - 1);
        Y[(((size_t)bb * Hv + hh) * Sv + ss) * DKv + dk] = f2bf(acc[m][n][r] * scale);
      }
}

// ---------------------------------------------------------------------------
// 3-term split-precision bf16 MFMA GEMM for the OUTPUT projection (fp32-grade,
// verified rounds 5-6). X,Wo given as split arrays [rows][2048] (hi|lo octets).
// ---------------------------------------------------------------------------
__global__ __launch_bounds__(256, 2)
void gemm_out_mfma(const ushort* __restrict__ Ag, const ushort* __restrict__ Wg,
                   float* __restrict__ out) {
  // bijective XCD swizzle: nwg = 256 = 8*32
  const int hid = (int)blockIdx.y * 8 + (int)blockIdx.x;
  const int id  = (hid & 7) * 32 + (hid >> 3);
  const int bn = id & 7;
  const int bm = id >> 3;

  __shared__ __align__(16) ushort AT[128 * 128];
  __shared__ __align__(16) ushort WT[128 * 128];

  const int tid  = threadIdx.x;
  const int lane = tid & 63;
  const int wid  = tid >> 6;
  const int wr = wid >> 1, wc = wid & 1;
  const int c = lane & 15, g = lane >> 4;

  f32x4 acc[4][4];
#pragma unroll
  for (int m = 0; m < 4; ++m)
#pragma unroll
    for (int n = 0; n < 4; ++n) acc[m][n] = (f32x4){0.f, 0.f, 0.f, 0.f};

  const int srow  = tid >> 4;
  const int sslot = tid & 15;
  const size_t aBase = (size_t)(bm * 128 + srow) * 2048 + sslot * 8;
  const size_t wBase = (size_t)(bn * 128 + srow) * 2048 + sslot * 8;
  const int sb = srow * 256 + ((sslot * 16) ^ ((srow & 7) << 4));

  for (int kt = 0; kt < 16; ++kt) {
    __syncthreads();
#pragma unroll
    for (int it = 0; it < 8; ++it)
      *reinterpret_cast<uint4*>((char*)AT + it * 4096 + sb) =
          *reinterpret_cast<const uint4*>(Ag + aBase + (size_t)it * 32768 + kt * 128);
#pragma unroll
    for (int it = 0; it < 8; ++it)
      *reinterpret_cast<uint4*>((char*)WT + it * 4096 + sb) =
          *reinterpret_cast<const uint4*>(Wg + wBase + (size_t)it * 32768 + kt * 128);
    __syncthreads();

#pragma unroll
    for (int kk = 0; kk < 2; ++kk) {
      const int ob = (kk * 4 + g) * 32;
      bf16x8 bh[4], bl[4];
#pragma unroll
      for (int n = 0; n < 4; ++n) {
        const int row = wc * 64 + n * 16 + c;
        const char* p = (const char*)WT;
        bh[n] = *reinterpret_cast<const bf16x8*>(p + swz(row * 256 + ob, row));
        bl[n] = *reinterpret_cast<const bf16x8*>(p + swz(row * 256 + ob + 16, row));
      }
#pragma unroll
      for (int m = 0; m < 4; ++m) {
        const int row = wr * 64 + m * 16 + c;
        const char* p = (const char*)AT;
        const bf16x8 ah = *reinterpret_cast<const bf16x8*>(p + swz(row * 256 + ob, row));
        const bf16x8 al = *reinterpret_cast<const bf16x8*>(p + swz(row * 256 + ob + 16, row));
#pragma unroll
        for (int n = 0; n < 4; ++n) {
          acc[m][n] = __builtin_amdgcn_mfma_f32_16x16x32_bf16(ah, bh[n], acc[m][n], 0, 0, 0);
          acc[m][n] = __builtin_amdgcn_mfma_f32_16x16x32_bf16(al, bh[n], acc[m][n], 0, 0, 0);
          acc[m][n] = __builtin_amdgcn_mfma_f32_16x16x32_bf16(ah, bl[n], acc[m][n], 0, 0, 0);
        }
      }
    }
  }

#pragma unroll
  for (int m = 0; m < 4; ++m)
#pragma unroll
    for (int n = 0; n < 4; ++n)
#pragma unroll
      for (int r = 0; r < 4; ++r) {
        const int tok = bm * 128 + wr * 64 + m * 16 + 4 * g + r;
        const int e   = bn * 128 + wc * 64 + n * 16 + c;
        out[(size_t)tok * Dv + e] = acc[m][n][r];
      }
}

// ---------------------------------------------------------------------------
// Causal flash attention, bf16 MFMA, double-buffered + reg-prefetch.
// (verified round 6; unchanged)
// ---------------------------------------------------------------------------
__global__ __launch_bounds__(256)
void attn_fwd_mfma(const ushort* __restrict__ Q, const ushort* __restrict__ K,
                   const ushort* __restrict__ V, float* __restrict__ X) {
  const int tid  = threadIdx.x;
  const int lane = tid & 63;
  const int w    = tid >> 6;        // wave 0..3
  const int c    = lane & 15;
  const int g    = lane >> 4;
  const int qt = (int)gridDim.x - 1 - (int)blockIdx.x;  // long blocks first
  const int bh = blockIdx.y;
  const int b = bh >> 4, h = bh & (Hv - 1);
  const int qtk = 2 * qt + 1;       // last KV tile index

  const ushort* Qb = Q + (size_t)bh * Sv * DKv;
  const ushort* Kb = K + (size_t)bh * Sv * DKv;
  const ushort* Vb = V + (size_t)bh * Sv * DKv;

  __shared__ __align__(16) char lds[49152];
  // K buf i: lds + i*8192; V buf i: lds + 16384 + i*8192; P: lds+32768+w*4096
  // Q overlays [0, 16384) during init only.

#pragma unroll
  for (int l = 0; l < 2; ++l) {
    const int r  = l * 64 + (tid >> 2);
    const int c0 = (tid & 3) << 4;
    const ushort* src = Qb + (size_t)(qt * 128 + r) * DKv + c0;
    uint4 v0 = *reinterpret_cast<const uint4*>(src);
    uint4 v1 = *reinterpret_cast<const uint4*>(src + 8);
    *reinterpret_cast<uint4*>(lds + swz(r * 128 + 2 * c0, r))      = v0;
    *reinterpret_cast<uint4*>(lds + swz(r * 128 + 2 * c0 + 16, r)) = v1;
  }
  __syncthreads();

  bf16x8 qf0[2], qf1[2];
#pragma unroll
  for (int m = 0; m < 2; ++m) {
    const int qr = w * 32 + m * 16 + c;
    qf0[m] = *reinterpret_cast<const bf16x8*>(lds + swz(qr * 128 + 16 * g, qr));
    qf1[m] = *reinterpret_cast<const bf16x8*>(lds + swz(qr * 128 + 64 + 16 * g, qr));
  }

  const int kr_s  = tid >> 2;
  const int kc_s  = (tid & 3) << 4;
  const int vi_s  = tid & 31;
  const int vc_s  = (tid >> 5) << 3;

  uint4 kA, kB, vA, vB;
  {
    const ushort* ks = Kb + (size_t)kr_s * DKv + kc_s;
    kA = *reinterpret_cast<const uint4*>(ks);
    kB = *reinterpret_cast<const uint4*>(ks + 8);
    const ushort* vs = Vb + (size_t)(2 * vi_s) * DKv + vc_s;
    vA = *reinterpret_cast<const uint4*>(vs);
    vB = *reinterpret_cast<const uint4*>(vs + DKv);
  }
  __syncthreads();

  {
    char* kd = lds;
    *reinterpret_cast<uint4*>(kd + swz(kr_s * 128 + 2 * kc_s, kr_s))      = kA;
    *reinterpret_cast<uint4*>(kd + swz(kr_s * 128 + 2 * kc_s + 16, kr_s)) = kB;
    char* vd = lds + 16384;
    unsigned int ee[4] = {vA.x, vA.y, vA.z, vA.w};
    unsigned int oo[4] = {vB.x, vB.y, vB.z, vB.w};
#pragma unroll
    for (int p = 0; p < 4; ++p) {
      unsigned int lo = (ee[p] & 0xffffu) | (oo[p] << 16);
      unsigned int hi = (ee[p] >> 16) | (oo[p] & 0xffff0000u);
      const int d0 = vc_s + 2 * p;
      *reinterpret_cast<unsigned int*>(vd + swz(d0 * 128 + 4 * vi_s, d0))           = lo;
      *reinterpret_cast<unsigned int*>(vd + swz((d0 + 1) * 128 + 4 * vi_s, d0 + 1)) = hi;
    }
  }
  __syncthreads();

  f32x4 accO[2][4];
#pragma unroll
  for (int m = 0; m < 2; ++m)
#pragma unroll
    for (int ds = 0; ds < 4; ++ds) accO[m][ds] = (f32x4){0.f, 0.f, 0.f, 0.f};
  float mS[2] = {-3.0e38f, -3.0e38f};
  float lS[2] = {0.f, 0.f};

  for (int kv = 0; kv <= qtk; ++kv) {
    const int cur = kv & 1;

    if (kv < qtk) {
      const ushort* ks = Kb + (size_t)((kv + 1) * 64 + kr_s) * DKv + kc_s;
      kA = *reinterpret_cast<const uint4*>(ks);
      kB = *reinterpret_cast<const uint4*>(ks + 8);
      const ushort* vs = Vb + (size_t)((kv + 1) * 64 + 2 * vi_s) * DKv + vc_s;
      vA = *reinterpret_cast<const uint4*>(vs);
      vB = *reinterpret_cast<const uint4*>(vs + DKv);
    }

    const char* kbase = lds + cur * 8192;
    const char* vbase = lds + 16384 + cur * 8192;
    char* pbase = lds + 32768 + w * 4096;

    f32x4 s[2][4];
#pragma unroll
    for (int kt = 0; kt < 4; ++kt) {
      const int kr = kt * 16 + c;
      bf16x8 kf0 = *reinterpret_cast<const bf16x8*>(kbase + swz(kr * 128 + 16 * g, kr));
      bf16x8 kf1 = *reinterpret_cast<const bf16x8*>(kbase + swz(kr * 128 + 64 + 16 * g, kr));
#pragma unroll
      for (int m = 0; m < 2; ++m) {
        f32x4 z = (f32x4){0.f, 0.f, 0.f, 0.f};
        z = __builtin_amdgcn_mfma_f32_16x16x32_bf16(kf0, qf0[m], z, 0, 0, 0);
        s[m][kt] = __builtin_amdgcn_mfma_f32_16x16x32_bf16(kf1, qf1[m], z, 0, 0, 0);
      }
    }

    if (kv >= 2 * qt) {
#pragma unroll
      for (int m = 0; m < 2; ++m) {
        const int ql = qt * 128 + w * 32 + m * 16 + c;
#pragma unroll
        for (int kt = 0; kt < 4; ++kt)
#pragma unroll
          for (int rr = 0; rr < 4; ++rr) {
            const int kl = kv * 64 + kt * 16 + 4 * g + rr;
            if (kl > ql) s[m][kt][rr] = -3.0e38f;
          }
      }
    }

    float corrM[2];
#pragma unroll
    for (int m = 0; m < 2; ++m) {
      float tm = -3.0e38f;
#pragma unroll
      for (int kt = 0; kt < 4; ++kt)
#pragma unroll
        for (int rr = 0; rr < 4; ++rr) tm = fmaxf(tm, s[m][kt][rr]);
      tm = fmaxf(tm, __shfl_xor(tm, 16));
      tm = fmaxf(tm, __shfl_xor(tm, 32));
      const float mnew = fmaxf(mS[m], tm);
      corrM[m] = fast_exp2(mS[m] - mnew);
      mS[m] = mnew;

      float psum = 0.f;
#pragma unroll
      for (int kt = 0; kt < 4; ++kt)
#pragma unroll
        for (int rr = 0; rr < 4; ++rr) {
          const float p = fast_exp2(s[m][kt][rr] - mnew);
          s[m][kt][rr] = p;
          psum += p;
        }
      psum += __shfl_xor(psum, 16);
      psum += __shfl_xor(psum, 32);
      lS[m] = lS[m] * corrM[m] + psum;

      const int pr = m * 16 + c;
#pragma unroll
      for (int kt = 0; kt < 4; ++kt) {
        unsigned int lo = (unsigned int)f2bf(s[m][kt][0]) | ((unsigned int)f2bf(s[m][kt][1]) << 16);
        unsigned int hi = (unsigned int)f2bf(s[m][kt][2]) | ((unsigned int)f2bf(s[m][kt][3]) << 16);
        const int k0 = kt * 16 + 4 * g;
        *reinterpret_cast<unsigned int*>(pbase + swz(pr * 128 + 2 * k0, pr))     = lo;
        *reinterpret_cast<unsigned int*>(pbase + swz(pr * 128 + 2 * k0 + 4, pr)) = hi;
      }

      float corr4[4];
#pragma unroll
      for (int rr = 0; rr < 4; ++rr)
        corr4[rr] = __int_as_float(__builtin_amdgcn_ds_bpermute(
            (4 * g + rr) << 2, __float_as_int(corrM[m])));
#pragma unroll
      for (int ds = 0; ds < 4; ++ds)
#pragma unroll
        for (int rr = 0; rr < 4; ++rr) accO[m][ds][rr] *= corr4[rr];
    }

#pragma unroll
    for (int ks = 0; ks < 2; ++ks) {
      bf16x8 vf[4];
#pragma unroll
      for (int ds = 0; ds < 4; ++ds) {
        const int dk = ds * 16 + c;
        vf[ds] = *reinterpret_cast<const bf16x8*>(vbase + swz(dk * 128 + ks * 64 + 16 * g, dk));
      }
#pragma unroll
      for (int m = 0; m < 2; ++m) {
        const int pr = m * 16 + c;
        bf16x8 pf = *reinterpret_cast<const bf16x8*>(pbase + swz(pr * 128 + ks * 64 + 16 * g, pr));
#pragma unroll
        for (int ds = 0; ds < 4; ++ds)
          accO[m][ds] = __builtin_amdgcn_mfma_f32_16x16x32_bf16(pf, vf[ds], accO[m][ds], 0, 0, 0);
      }
    }

    if (kv < qtk) {
      char* kd = lds + (cur ^ 1) * 8192;
      *reinterpret_cast<uint4*>(kd + swz(kr_s * 128 + 2 * kc_s, kr_s))      = kA;
      *reinterpret_cast<uint4*>(kd + swz(kr_s * 128 + 2 * kc_s + 16, kr_s)) = kB;
      char* vd = lds + 16384 + (cur ^ 1) * 8192;
      unsigned int ee[4] = {vA.x, vA.y, vA.z, vA.w};
      unsigned int oo[4] = {vB.x, vB.y, vB.z, vB.w};
#pragma unroll
      for (int p = 0; p < 4; ++p) {
        unsigned int lo = (ee[p] & 0xffffu) | (oo[p] << 16);
        unsigned int hi = (ee[p] >> 16) | (oo[p] & 0xffff0000u);
        const int d0 = vc_s + 2 * p;
        *reinterpret_cast<unsigned int*>(vd + swz(d0 * 128 + 4 * vi_s, d0))           = lo;
        *reinterpret_cast<unsigned int*>(vd + swz((d0 + 1) * 128 + 4 * vi_s, d0 + 1)) = hi;
      }
    }
    __syncthreads();
  }

#pragma unroll
  for (int m = 0; m < 2; ++m) {
    const float inv = 1.0f / lS[m];
    float inv4[4];
#pragma unroll
    for (int rr = 0; rr < 4; ++rr)
      inv4[rr] = __int_as_float(__builtin_amdgcn_ds_bpermute(
          (4 * g + rr) << 2, __float_as_int(inv)));
    const int q0 = qt * 128 + w * 32 + m * 16;
#pragma unroll
    for (int ds = 0; ds < 4; ++ds)
#pragma unroll
      for (int rr = 0; rr < 4; ++rr) {
        const int srow = q0 + 4 * g + rr;
        X[((size_t)(b * Sv + srow)) * Dv + h * DKv + ds * 16 + c] = accO[m][ds][rr] * inv4[rr];
      }
  }
}

// ---------------------------------------------------------------------------
// launch
// ---------------------------------------------------------------------------
extern "C" void kernel_launch(void* const* d_in, const int* in_sizes, int n_in,
                              void* d_out, int out_size, void* d_ws, size_t ws_size,
                              hipStream_t stream) {
  const float* q  = (const float*)d_in[0];
  const float* k  = (const float*)d_in[1];
  const float* v  = (const float*)d_in[2];
  // d_in[3] = mask: causal tril, handled analytically
  const float* Wq = (const float*)d_in[4];
  const float* Wk = (const float*)d_in[5];
  const float* Wv = (const float*)d_in[6];
  const float* Wo = (const float*)d_in[7];
  float* out = (float*)d_out;

  // workspace layout (bytes)
  constexpr size_t SEG   = (size_t)NTOK * Dv;     // 4194304 elements
  constexpr size_t ACT_S = SEG * 2;               // bf16 act buffer    8.39MB
  constexpr size_t X_S   = SEG * 4;               // fp32 X            16.78MB
  constexpr size_t WB_S  = (size_t)Dv * Dv * 2;   // bf16 weight        2.10MB
  constexpr size_t SPW_S = (size_t)Dv * Dv * 4;   // split Wo           4.19MB

  char* ws = (char*)d_ws;
  ushort* Qw  = (ushort*)(ws);
  ushort* Kw  = (ushort*)(ws + ACT_S);
  ushort* Vw  = (ushort*)(ws + 2 * ACT_S);
  float*  Xw  = (float*) (ws + 3 * ACT_S);
  ushort* qB  = (ushort*)(ws + 3 * ACT_S + X_S);
  ushort* kB  = (ushort*)(ws + 3 * ACT_S + X_S + ACT_S);
  ushort* vB  = (ushort*)(ws + 3 * ACT_S + X_S + 2 * ACT_S);
  ushort* WqB = (ushort*)(ws + 3 * ACT_S + X_S + 3 * ACT_S);
  ushort* WkB = (ushort*)(ws + 3 * ACT_S + X_S + 3 * ACT_S + WB_S);
  ushort* WvB = (ushort*)(ws + 3 * ACT_S + X_S + 3 * ACT_S + 2 * WB_S);
  ushort* WoS = (ushort*)(ws + 3 * ACT_S + X_S + 3 * ACT_S + 3 * WB_S);
  ushort* XS  = (ushort*)(ws + 3 * ACT_S + X_S + 3 * ACT_S + 3 * WB_S + SPW_S);

  const dim3 blk(256);
  cast_split<<<dim3(NTOK * Dv / 8 / 256, 7), blk, 0, stream>>>(
      q, k, v, Wq, Wk, Wv, Wo, qB, kB, vB, WqB, WkB, WvB, WoS);
  gemm_qkv_bf16<<<dim3(8, 32, 3), blk, 0, stream>>>(
      qB, kB, vB, WqB, WkB, WvB, Qw, Kw, Vw);
  attn_fwd_mfma<<<dim3(Sv / 128, Bv * Hv), blk, 0, stream>>>(Qw, Kw, Vw, Xw);
  split1<<<dim3(NTOK * Dv / 8 / 256), blk, 0, stream>>>(Xw, XS);
  gemm_out_mfma<<<dim3(8, 32), blk, 0, stream>>>(XS, WoS, out);
}

// Round 8
// 239.152 us; speedup vs baseline: 8.3837x; 1.1520x over previous
//
#include <hip/hip_runtime.h>

// Problem constants (match reference)
constexpr int Bv  = 2;
constexpr int Sv  = 2048;
constexpr int Dv  = 1024;
constexpr int Hv  = 16;
constexpr int DKv = 64;
constexpr int NTOK = Bv * Sv;  // 4096

// Q is pre-scaled at projection time by 1/sqrt(DK) * log2(e) so attention
// scores are already in exp2 domain.
#define QSCALE 0.18033688011112042f  // 0.125 * 1.4426950408889634

typedef __attribute__((ext_vector_type(8))) short bf16x8;   // MFMA A/B frag (4 VGPR)
typedef __attribute__((ext_vector_type(4))) float f32x4;    // MFMA C/D frag

__device__ __forceinline__ ushort f2bf(float f) {
  // round-to-nearest-even fp32 -> bf16 (finite inputs only)
  unsigned int u = __float_as_uint(f);
  unsigned int r = (u + 0x7fffu + ((u >> 16) & 1u)) >> 16;
  return (ushort)r;
}

__device__ __forceinline__ float fast_exp2(float x) {
#if __has_builtin(__builtin_amdgcn_exp2f)
  return __builtin_amdgcn_exp2f(x);
#else
  return exp2f(x);
#endif
}

// XOR swizzle: permutes 16B blocks by row&7 (T2 / Guideline 4).
__device__ __forceinline__ int swz(int byte_linear, int row) {
  return byte_linear ^ ((row & 7) << 4);
}

// ---------------------------------------------------------------------------
// Precompute pass: casts (f32 -> bf16) and the Wo split.
// ---------------------------------------------------------------------------
__device__ __forceinline__ void cast_octet(const float* __restrict__ src,
                                           ushort* __restrict__ dst, int o) {
  const float4 f0 = *reinterpret_cast<const float4*>(src + (size_t)o * 8);
  const float4 f1 = *reinterpret_cast<const float4*>(src + (size_t)o * 8 + 4);
  uint4 u;
  u.x = (unsigned int)f2bf(f0.x) | ((unsigned int)f2bf(f0.y) << 16);
  u.y = (unsigned int)f2bf(f0.z) | ((unsigned int)f2bf(f0.w) << 16);
  u.z = (unsigned int)f2bf(f1.x) | ((unsigned int)f2bf(f1.y) << 16);
  u.w = (unsigned int)f2bf(f1.z) | ((unsigned int)f2bf(f1.w) << 16);
  *reinterpret_cast<uint4*>(dst + (size_t)o * 8) = u;
}

__device__ __forceinline__ void split_octet(const float* __restrict__ src,
                                            ushort* __restrict__ dst, int o) {
  const float4 f0 = *reinterpret_cast<const float4*>(src + (size_t)o * 8);
  const float4 f1 = *reinterpret_cast<const float4*>(src + (size_t)o * 8 + 4);
  float xs[8] = {f0.x, f0.y, f0.z, f0.w, f1.x, f1.y, f1.z, f1.w};
  unsigned int hp[4], lp[4];
#pragma unroll
  for (int j = 0; j < 4; ++j) {
    const unsigned int u0 = __float_as_uint(xs[2 * j]);
    const unsigned int u1 = __float_as_uint(xs[2 * j + 1]);
    const unsigned int h0 = u0 & 0xffff0000u;
    const unsigned int h1 = u1 & 0xffff0000u;
    hp[j] = (h0 >> 16) | h1;
    const float r0 = xs[2 * j] - __uint_as_float(h0);
    const float r1 = xs[2 * j + 1] - __uint_as_float(h1);
    lp[j] = (__float_as_uint(r0) >> 16) | (__float_as_uint(r1) & 0xffff0000u);
  }
  uint4* d = reinterpret_cast<uint4*>(dst + (size_t)o * 16);
  d[0] = make_uint4(hp[0], hp[1], hp[2], hp[3]);
  d[1] = make_uint4(lp[0], lp[1], lp[2], lp[3]);
}

// y = 0..2: cast q,k,v; y = 3..5: cast Wq,Wk,Wv; y = 6: split Wo.
__global__ __launch_bounds__(256)
void cast_split(const float* __restrict__ q, const float* __restrict__ k,
                const float* __restrict__ v, const float* __restrict__ Wq,
                const float* __restrict__ Wk, const float* __restrict__ Wv,
                const float* __restrict__ Wo,
                ushort* __restrict__ qB, ushort* __restrict__ kB,
                ushort* __restrict__ vB, ushort* __restrict__ WqB,
                ushort* __restrict__ WkB, ushort* __restrict__ WvB,
                ushort* __restrict__ WoS) {
  const int o = blockIdx.x * 256 + threadIdx.x;
  constexpr int NA = NTOK * Dv / 8;  // 524288
  constexpr int NW = Dv * Dv / 8;    // 131072
  switch (blockIdx.y) {
    case 0: if (o < NA) cast_octet(q, qB, o); break;
    case 1: if (o < NA) cast_octet(k, kB, o); break;
    case 2: if (o < NA) cast_octet(v, vB, o); break;
    case 3: if (o < NW) cast_octet(Wq, WqB, o); break;
    case 4: if (o < NW) cast_octet(Wk, WkB, o); break;
    case 5: if (o < NW) cast_octet(Wv, WvB, o); break;
    default: if (o < NW) split_octet(Wo, WoS, o); break;
  }
}

// ---------------------------------------------------------------------------
// Plain bf16 MFMA GEMM for Q/K/V projections (verified r7: error-neutral).
// ---------------------------------------------------------------------------
__global__ __launch_bounds__(256, 2)
void gemm_qkv_bf16(const ushort* __restrict__ qB, const ushort* __restrict__ kB,
                   const ushort* __restrict__ vB,
                   const ushort* __restrict__ WqB, const ushort* __restrict__ WkB,
                   const ushort* __restrict__ WvB,
                   ushort* __restrict__ Qw, ushort* __restrict__ Kw,
                   ushort* __restrict__ Vw) {
  // bijective XCD swizzle: nwg = 768 = 8*96
  const int hid = (int)blockIdx.z * 256 + (int)blockIdx.y * 8 + (int)blockIdx.x;
  const int id  = (hid & 7) * 96 + (hid >> 3);
  const int bn = id & 7;
  const int bm = (id >> 3) & 31;
  const int bz = id >> 8;

  const ushort* Ag;
  const ushort* Wg;
  ushort* Y;
  float scale = 1.0f;
  if (bz == 0)      { Ag = qB; Wg = WqB; Y = Qw; scale = QSCALE; }
  else if (bz == 1) { Ag = kB; Wg = WkB; Y = Kw; }
  else              { Ag = vB; Wg = WvB; Y = Vw; }

  __shared__ __align__(16) ushort AT[128 * 128];
  __shared__ __align__(16) ushort WT[128 * 128];

  const int tid  = threadIdx.x;
  const int lane = tid & 63;
  const int wid  = tid >> 6;
  const int wr = wid >> 1, wc = wid & 1;
  const int c = lane & 15, g = lane >> 4;

  f32x4 acc[4][4];
#pragma unroll
  for (int m = 0; m < 4; ++m)
#pragma unroll
    for (int n = 0; n < 4; ++n) acc[m][n] = (f32x4){0.f, 0.f, 0.f, 0.f};

  const int srow  = tid >> 4;
  const int sslot = tid & 15;
  const size_t aBase = (size_t)(bm * 128 + srow) * 1024 + sslot * 8;
  const size_t wBase = (size_t)(bn * 128 + srow) * 1024 + sslot * 8;
  const int sb = srow * 256 + ((sslot * 16) ^ ((srow & 7) << 4));

  for (int kt = 0; kt < 8; ++kt) {  // BK = 128
    __syncthreads();
#pragma unroll
    for (int it = 0; it < 8; ++it)
      *reinterpret_cast<uint4*>((char*)AT + it * 4096 + sb) =
          *reinterpret_cast<const uint4*>(Ag + aBase + (size_t)it * 16384 + kt * 128);
#pragma unroll
    for (int it = 0; it < 8; ++it)
      *reinterpret_cast<uint4*>((char*)WT + it * 4096 + sb) =
          *reinterpret_cast<const uint4*>(Wg + wBase + (size_t)it * 16384 + kt * 128);
    __syncthreads();

#pragma unroll
    for (int kk = 0; kk < 4; ++kk) {
      const int ob = kk * 64 + 16 * g;
      bf16x8 bh[4];
#pragma unroll
      for (int n = 0; n < 4; ++n) {
        const int row = wc * 64 + n * 16 + c;
        bh[n] = *reinterpret_cast<const bf16x8*>((const char*)WT + swz(row * 256 + ob, row));
      }
#pragma unroll
      for (int m = 0; m < 4; ++m) {
        const int row = wr * 64 + m * 16 + c;
        const bf16x8 ah = *reinterpret_cast<const bf16x8*>((const char*)AT + swz(row * 256 + ob, row));
#pragma unroll
        for (int n = 0; n < 4; ++n)
          acc[m][n] = __builtin_amdgcn_mfma_f32_16x16x32_bf16(ah, bh[n], acc[m][n], 0, 0, 0);
      }
    }
  }

#pragma unroll
  for (int m = 0; m < 4; ++m)
#pragma unroll
    for (int n = 0; n < 4; ++n)
#pragma unroll
      for (int r = 0; r < 4; ++r) {
        const int tok = bm * 128 + wr * 64 + m * 16 + 4 * g + r;
        const int e   = bn * 128 + wc * 64 + n * 16 + c;
        const int bb = tok >> 11, ss = tok & (Sv - 1);
        const int hh = e >> 6, dk = e & (DKv - 1);
        Y[(((size_t)bb * Hv + hh) * Sv + ss) * DKv + dk] = f2bf(acc[m][n][r] * scale);
      }
}

// ---------------------------------------------------------------------------
// 3-term split-precision bf16 MFMA GEMM for the OUTPUT projection
// (fp32-grade; verified rounds 5-7).
// ---------------------------------------------------------------------------
__global__ __launch_bounds__(256, 2)
void gemm_out_mfma(const ushort* __restrict__ Ag, const ushort* __restrict__ Wg,
                   float* __restrict__ out) {
  const int hid = (int)blockIdx.y * 8 + (int)blockIdx.x;
  const int id  = (hid & 7) * 32 + (hid >> 3);
  const int bn = id & 7;
  const int bm = id >> 3;

  __shared__ __align__(16) ushort AT[128 * 128];
  __shared__ __align__(16) ushort WT[128 * 128];

  const int tid  = threadIdx.x;
  const int lane = tid & 63;
  const int wid  = tid >> 6;
  const int wr = wid >> 1, wc = wid & 1;
  const int c = lane & 15, g = lane >> 4;

  f32x4 acc[4][4];
#pragma unroll
  for (int m = 0; m < 4; ++m)
#pragma unroll
    for (int n = 0; n < 4; ++n) acc[m][n] = (f32x4){0.f, 0.f, 0.f, 0.f};

  const int srow  = tid >> 4;
  const int sslot = tid & 15;
  const size_t aBase = (size_t)(bm * 128 + srow) * 2048 + sslot * 8;
  const size_t wBase = (size_t)(bn * 128 + srow) * 2048 + sslot * 8;
  const int sb = srow * 256 + ((sslot * 16) ^ ((srow & 7) << 4));

  for (int kt = 0; kt < 16; ++kt) {
    __syncthreads();
#pragma unroll
    for (int it = 0; it < 8; ++it)
      *reinterpret_cast<uint4*>((char*)AT + it * 4096 + sb) =
          *reinterpret_cast<const uint4*>(Ag + aBase + (size_t)it * 32768 + kt * 128);
#pragma unroll
    for (int it = 0; it < 8; ++it)
      *reinterpret_cast<uint4*>((char*)WT + it * 4096 + sb) =
          *reinterpret_cast<const uint4*>(Wg + wBase + (size_t)it * 32768 + kt * 128);
    __syncthreads();

#pragma unroll
    for (int kk = 0; kk < 2; ++kk) {
      const int ob = (kk * 4 + g) * 32;
      bf16x8 bh[4], bl[4];
#pragma unroll
      for (int n = 0; n < 4; ++n) {
        const int row = wc * 64 + n * 16 + c;
        const char* p = (const char*)WT;
        bh[n] = *reinterpret_cast<const bf16x8*>(p + swz(row * 256 + ob, row));
        bl[n] = *reinterpret_cast<const bf16x8*>(p + swz(row * 256 + ob + 16, row));
      }
#pragma unroll
      for (int m = 0; m < 4; ++m) {
        const int row = wr * 64 + m * 16 + c;
        const char* p = (const char*)AT;
        const bf16x8 ah = *reinterpret_cast<const bf16x8*>(p + swz(row * 256 + ob, row));
        const bf16x8 al = *reinterpret_cast<const bf16x8*>(p + swz(row * 256 + ob + 16, row));
#pragma unroll
        for (int n = 0; n < 4; ++n) {
          acc[m][n] = __builtin_amdgcn_mfma_f32_16x16x32_bf16(ah, bh[n], acc[m][n], 0, 0, 0);
          acc[m][n] = __builtin_amdgcn_mfma_f32_16x16x32_bf16(al, bh[n], acc[m][n], 0, 0, 0);
          acc[m][n] = __builtin_amdgcn_mfma_f32_16x16x32_bf16(ah, bl[n], acc[m][n], 0, 0, 0);
        }
      }
    }
  }

#pragma unroll
  for (int m = 0; m < 4; ++m)
#pragma unroll
    for (int n = 0; n < 4; ++n)
#pragma unroll
      for (int r = 0; r < 4; ++r) {
        const int tok = bm * 128 + wr * 64 + m * 16 + 4 * g + r;
        const int e   = bn * 128 + wc * 64 + n * 16 + c;
        out[(size_t)tok * Dv + e] = acc[m][n][r];
      }
}

// ---------------------------------------------------------------------------
// Causal flash attention, bf16 MFMA, double-buffered + reg-prefetch.
// BALANCED: 256 blocks x 8 waves (512 thr). Block i processes work items
// i and 511-i of the qt-sorted (bh,qt) list -> qt_a + qt_b = 15, so EVERY
// block runs exactly 34 KV-tile iterations regardless of CU assignment
// (fixes the r7 makespan imbalance: same-qt blocks were CU-paired, 32 vs 17
// units). Each wave owns 16 q-rows. Epilogue writes X directly in split
// hi/lo octet layout (replaces the split1 kernel; identical truncation).
// LDS 48KB: K dbuf 16K | V dbuf 16K | P 16K (8 waves x 2KB).
// ---------------------------------------------------------------------------
__global__ __launch_bounds__(512)
void attn_fwd_mfma(const ushort* __restrict__ Q, const ushort* __restrict__ K,
                   const ushort* __restrict__ V, ushort* __restrict__ XS) {
  const int tid  = threadIdx.x;
  const int lane = tid & 63;
  const int w    = tid >> 6;        // wave 0..7
  const int c    = lane & 15;
  const int g    = lane >> 4;

  __shared__ __align__(16) char lds[49152];

  // staging address components (fixed across items)
  const int kr_s = tid >> 3;             // K row 0..63
  const int kcb  = (tid & 7) << 4;       // K byte col 0..112
  const bool vwork = (tid < 256);        // waves 0-3 stage V (wave-uniform)
  const int vi_s = tid & 31;             // V row pair 0..31
  const int vc_s = ((tid >> 5) & 7) << 3;  // V dk col 0,8,..,56

#pragma unroll 1
  for (int item = 0; item < 2; ++item) {
    const int idx = (item == 0) ? (int)blockIdx.x : 511 - (int)blockIdx.x;
    const int qt = idx >> 5;       // item0: 0..7, item1: 8..15
    const int bh = idx & 31;
    const int b = bh >> 4, h = bh & (Hv - 1);
    const int qtk = 2 * qt + 1;    // last KV tile index

    const ushort* Qb = Q + (size_t)bh * Sv * DKv;
    const ushort* Kb = K + (size_t)bh * Sv * DKv;
    const ushort* Vb = V + (size_t)bh * Sv * DKv;

    // ---- stage Q (128 rows x 128B) into K-dbuf region ----
    {
      const int r  = tid >> 2;             // 0..127
      const int c0 = (tid & 3) << 4;       // bf16 col
      const ushort* src = Qb + (size_t)(qt * 128 + r) * DKv + c0;
      uint4 v0 = *reinterpret_cast<const uint4*>(src);
      uint4 v1 = *reinterpret_cast<const uint4*>(src + 8);
      *reinterpret_cast<uint4*>(lds + swz(r * 128 + 2 * c0, r))      = v0;
      *reinterpret_cast<uint4*>(lds + swz(r * 128 + 2 * c0 + 16, r)) = v1;
    }
    __syncthreads();

    // ---- Q frags (B-operand), wave w owns q-rows w*16..w*16+15 ----
    bf16x8 qf0, qf1;
    {
      const int qr = w * 16 + c;
      qf0 = *reinterpret_cast<const bf16x8*>(lds + swz(qr * 128 + 16 * g, qr));
      qf1 = *reinterpret_cast<const bf16x8*>(lds + swz(qr * 128 + 64 + 16 * g, qr));
    }

    uint4 kA, vA, vB;
    kA = *reinterpret_cast<const uint4*>((const char*)Kb + (size_t)kr_s * 128 + kcb);
    if (vwork) {
      const ushort* vs = Vb + (size_t)(2 * vi_s) * DKv + vc_s;
      vA = *reinterpret_cast<const uint4*>(vs);
      vB = *reinterpret_cast<const uint4*>(vs + DKv);
    }
    __syncthreads();  // all waves done reading Q region before K write

    // ---- write tile 0 into buf 0 ----
    *reinterpret_cast<uint4*>(lds + swz(kr_s * 128 + kcb, kr_s)) = kA;
    if (vwork) {
      char* vd = lds + 16384;
      unsigned int ee[4] = {vA.x, vA.y, vA.z, vA.w};
      unsigned int oo[4] = {vB.x, vB.y, vB.z, vB.w};
#pragma unroll
      for (int p = 0; p < 4; ++p) {
        unsigned int lo = (ee[p] & 0xffffu) | (oo[p] << 16);
        unsigned int hi = (ee[p] >> 16) | (oo[p] & 0xffff0000u);
        const int d0 = vc_s + 2 * p;
        *reinterpret_cast<unsigned int*>(vd + swz(d0 * 128 + 4 * vi_s, d0))           = lo;
        *reinterpret_cast<unsigned int*>(vd + swz((d0 + 1) * 128 + 4 * vi_s, d0 + 1)) = hi;
      }
    }
    __syncthreads();

    f32x4 accO[4];
#pragma unroll
    for (int ds = 0; ds < 4; ++ds) accO[ds] = (f32x4){0.f, 0.f, 0.f, 0.f};
    float mS = -3.0e38f, lS = 0.f;

    for (int kv = 0; kv <= qtk; ++kv) {
      const int cur = kv & 1;

      // ---- issue next tile's global loads ----
      if (kv < qtk) {
        kA = *reinterpret_cast<const uint4*>(
            (const char*)Kb + ((size_t)(kv + 1) * 64 + kr_s) * 128 + kcb);
        if (vwork) {
          const ushort* vs = Vb + (size_t)((kv + 1) * 64 + 2 * vi_s) * DKv + vc_s;
          vA = *reinterpret_cast<const uint4*>(vs);
          vB = *reinterpret_cast<const uint4*>(vs + DKv);
        }
      }

      const char* kbase = lds + cur * 8192;
      const char* vbase = lds + 16384 + cur * 8192;
      char* pbase = lds + 32768 + w * 2048;

      // ---- QK^T (swapped): lane owns q = w*16+c, key = kv*64 + kt*16+4g+rr ----
      f32x4 s[4];
#pragma unroll
      for (int kt = 0; kt < 4; ++kt) {
        const int kr = kt * 16 + c;
        bf16x8 kf0 = *reinterpret_cast<const bf16x8*>(kbase + swz(kr * 128 + 16 * g, kr));
        bf16x8 kf1 = *reinterpret_cast<const bf16x8*>(kbase + swz(kr * 128 + 64 + 16 * g, kr));
        f32x4 z = (f32x4){0.f, 0.f, 0.f, 0.f};
        z = __builtin_amdgcn_mfma_f32_16x16x32_bf16(kf0, qf0, z, 0, 0, 0);
        s[kt] = __builtin_amdgcn_mfma_f32_16x16x32_bf16(kf1, qf1, z, 0, 0, 0);
      }

      // ---- causal mask (diagonal region only) ----
      if (kv >= 2 * qt) {
        const int ql = qt * 128 + w * 16 + c;
#pragma unroll
        for (int kt = 0; kt < 4; ++kt)
#pragma unroll
          for (int rr = 0; rr < 4; ++rr) {
            const int kl = kv * 64 + kt * 16 + 4 * g + rr;
            if (kl > ql) s[kt][rr] = -3.0e38f;
          }
      }

      // ---- online softmax (exp2 domain) ----
      float tm = -3.0e38f;
#pragma unroll
      for (int kt = 0; kt < 4; ++kt)
#pragma unroll
        for (int rr = 0; rr < 4; ++rr) tm = fmaxf(tm, s[kt][rr]);
      tm = fmaxf(tm, __shfl_xor(tm, 16));
      tm = fmaxf(tm, __shfl_xor(tm, 32));
      const float mnew = fmaxf(mS, tm);
      const float corr = fast_exp2(mS - mnew);
      mS = mnew;

      float psum = 0.f;
#pragma unroll
      for (int kt = 0; kt < 4; ++kt)
#pragma unroll
        for (int rr = 0; rr < 4; ++rr) {
          const float p = fast_exp2(s[kt][rr] - mnew);
          s[kt][rr] = p;
          psum += p;
        }
      psum += __shfl_xor(psum, 16);
      psum += __shfl_xor(psum, 32);
      lS = lS * corr + psum;

      // ---- P -> wave-private LDS (bf16, row = q = c) ----
#pragma unroll
      for (int kt = 0; kt < 4; ++kt) {
        unsigned int lo = (unsigned int)f2bf(s[kt][0]) | ((unsigned int)f2bf(s[kt][1]) << 16);
        unsigned int hi = (unsigned int)f2bf(s[kt][2]) | ((unsigned int)f2bf(s[kt][3]) << 16);
        const int k0 = kt * 16 + 4 * g;
        *reinterpret_cast<unsigned int*>(pbase + swz(c * 128 + 2 * k0, c))     = lo;
        *reinterpret_cast<unsigned int*>(pbase + swz(c * 128 + 2 * k0 + 4, c)) = hi;
      }

      // ---- rescale accO: acc reg rr holds q = 4g+rr; corr lives in lane q ----
      float corr4[4];
#pragma unroll
      for (int rr = 0; rr < 4; ++rr)
        corr4[rr] = __int_as_float(__builtin_amdgcn_ds_bpermute(
            (4 * g + rr) << 2, __float_as_int(corr)));
#pragma unroll
      for (int ds = 0; ds < 4; ++ds)
#pragma unroll
        for (int rr = 0; rr < 4; ++rr) accO[ds][rr] *= corr4[rr];

      // ---- PV ----
#pragma unroll
      for (int ks = 0; ks < 2; ++ks) {
        bf16x8 pf = *reinterpret_cast<const bf16x8*>(pbase + swz(c * 128 + ks * 64 + 16 * g, c));
#pragma unroll
        for (int ds = 0; ds < 4; ++ds) {
          const int dk = ds * 16 + c;
          bf16x8 vf = *reinterpret_cast<const bf16x8*>(vbase + swz(dk * 128 + ks * 64 + 16 * g, dk));
          accO[ds] = __builtin_amdgcn_mfma_f32_16x16x32_bf16(pf, vf, accO[ds], 0, 0, 0);
        }
      }

      // ---- write next tile into alternate buffer ----
      if (kv < qtk) {
        char* kd = lds + (cur ^ 1) * 8192;
        *reinterpret_cast<uint4*>(kd + swz(kr_s * 128 + kcb, kr_s)) = kA;
        if (vwork) {
          char* vd = lds + 16384 + (cur ^ 1) * 8192;
          unsigned int ee[4] = {vA.x, vA.y, vA.z, vA.w};
          unsigned int oo[4] = {vB.x, vB.y, vB.z, vB.w};
#pragma unroll
          for (int p = 0; p < 4; ++p) {
            unsigned int lo = (ee[p] & 0xffffu) | (oo[p] << 16);
            unsigned int hi = (ee[p] >> 16) | (oo[p] & 0xffff0000u);
            const int d0 = vc_s + 2 * p;
            *reinterpret_cast<unsigned int*>(vd + swz(d0 * 128 + 4 * vi_s, d0))           = lo;
            *reinterpret_cast<unsigned int*>(vd + swz((d0 + 1) * 128 + 4 * vi_s, d0 + 1)) = hi;
          }
        }
      }
      __syncthreads();
    }

    // ---- epilogue: write X directly in split hi/lo octet layout ----
    // XS[tok][oct*16 + j] = hi(X[tok][oct*8+j]); +8 = lo (truncation, matches
    // split_octet exactly -> gemm_out numerics unchanged).
    {
      const float inv = 1.0f / lS;
      float inv4[4];
#pragma unroll
      for (int rr = 0; rr < 4; ++rr)
        inv4[rr] = __int_as_float(__builtin_amdgcn_ds_bpermute(
            (4 * g + rr) << 2, __float_as_int(inv)));
      const int q0 = qt * 128 + w * 16;
#pragma unroll
      for (int ds = 0; ds < 4; ++ds) {
        const int e   = h * DKv + ds * 16 + c;          // column in [0,1024)
        const int oct = e >> 3, j = e & 7;
#pragma unroll
        for (int rr = 0; rr < 4; ++rr) {
          const int srow = q0 + 4 * g + rr;
          const float y = accO[ds][rr] * inv4[rr];
          const unsigned int u  = __float_as_uint(y);
          const unsigned int hb = u & 0xffff0000u;
          const float rlo = y - __uint_as_float(hb);
          ushort* d = XS + ((size_t)(b * Sv + srow)) * 2048 + oct * 16 + j;
          d[0] = (ushort)(u >> 16);
          d[8] = (ushort)(__float_as_uint(rlo) >> 16);
        }
      }
    }
    if (item == 0) __syncthreads();  // LDS reuse safety before next item's Q stage
  }
}

// ---------------------------------------------------------------------------
// launch
// ---------------------------------------------------------------------------
extern "C" void kernel_launch(void* const* d_in, const int* in_sizes, int n_in,
                              void* d_out, int out_size, void* d_ws, size_t ws_size,
                              hipStream_t stream) {
  const float* q  = (const float*)d_in[0];
  const float* k  = (const float*)d_in[1];
  const float* v  = (const float*)d_in[2];
  // d_in[3] = mask: causal tril, handled analytically
  const float* Wq = (const float*)d_in[4];
  const float* Wk = (const float*)d_in[5];
  const float* Wv = (const float*)d_in[6];
  const float* Wo = (const float*)d_in[7];
  float* out = (float*)d_out;

  constexpr size_t SEG   = (size_t)NTOK * Dv;
  constexpr size_t ACT_S = SEG * 2;               // bf16 act buffer
  constexpr size_t X_S   = SEG * 4;               // (spare)
  constexpr size_t WB_S  = (size_t)Dv * Dv * 2;   // bf16 weight
  constexpr size_t SPW_S = (size_t)Dv * Dv * 4;   // split Wo

  char* ws = (char*)d_ws;
  ushort* Qw  = (ushort*)(ws);
  ushort* Kw  = (ushort*)(ws + ACT_S);
  ushort* Vw  = (ushort*)(ws + 2 * ACT_S);
  ushort* qB  = (ushort*)(ws + 3 * ACT_S + X_S);
  ushort* kB  = (ushort*)(ws + 3 * ACT_S + X_S + ACT_S);
  ushort* vB  = (ushort*)(ws + 3 * ACT_S + X_S + 2 * ACT_S);
  ushort* WqB = (ushort*)(ws + 3 * ACT_S + X_S + 3 * ACT_S);
  ushort* WkB = (ushort*)(ws + 3 * ACT_S + X_S + 3 * ACT_S + WB_S);
  ushort* WvB = (ushort*)(ws + 3 * ACT_S + X_S + 3 * ACT_S + 2 * WB_S);
  ushort* WoS = (ushort*)(ws + 3 * ACT_S + X_S + 3 * ACT_S + 3 * WB_S);
  ushort* XS  = (ushort*)(ws + 3 * ACT_S + X_S + 3 * ACT_S + 3 * WB_S + SPW_S);

  const dim3 blk(256);
  cast_split<<<dim3(NTOK * Dv / 8 / 256, 7), blk, 0, stream>>>(
      q, k, v, Wq, Wk, Wv, Wo, qB, kB, vB, WqB, WkB, WvB, WoS);
  gemm_qkv_bf16<<<dim3(8, 32, 3), blk, 0, stream>>>(
      qB, kB, vB, WqB, WkB, WvB, Qw, Kw, Vw);
  attn_fwd_mfma<<<dim3(256), dim3(512), 0, stream>>>(Qw, Kw, Vw, XS);
  gemm_out_mfma<<<dim3(8, 32), blk, 0, stream>>>(XS, WoS, out);
}

// Round 9
// 233.892 us; speedup vs baseline: 8.5723x; 1.0225x over previous
//
#include <hip/hip_runtime.h>

// Problem constants (match reference)
constexpr int Bv  = 2;
constexpr int Sv  = 2048;
constexpr int Dv  = 1024;
constexpr int Hv  = 16;
constexpr int DKv = 64;
constexpr int NTOK = Bv * Sv;  // 4096

// Q is pre-scaled at projection time by 1/sqrt(DK) * log2(e) so attention
// scores are already in exp2 domain.
#define QSCALE 0.18033688011112042f  // 0.125 * 1.4426950408889634

typedef __attribute__((ext_vector_type(8))) short bf16x8;   // MFMA A/B frag (4 VGPR)
typedef __attribute__((ext_vector_type(4))) float f32x4;    // MFMA C/D frag

__device__ __forceinline__ ushort f2bf(float f) {
  // round-to-nearest-even fp32 -> bf16 (finite inputs only)
  unsigned int u = __float_as_uint(f);
  unsigned int r = (u + 0x7fffu + ((u >> 16) & 1u)) >> 16;
  return (ushort)r;
}

__device__ __forceinline__ float fast_exp2(float x) {
#if __has_builtin(__builtin_amdgcn_exp2f)
  return __builtin_amdgcn_exp2f(x);
#else
  return exp2f(x);
#endif
}

// XOR swizzle: permutes 16B blocks by row&7 (T2 / Guideline 4).
__device__ __forceinline__ int swz(int byte_linear, int row) {
  return byte_linear ^ ((row & 7) << 4);
}

// Async global->LDS 16B: wave-uniform LDS base, HW adds lane*16 (m97 lever).
#if defined(__has_builtin) && __has_builtin(__builtin_amdgcn_global_load_lds)
#define HAS_GLOAD_LDS 1
__device__ __forceinline__ void gload16(const ushort* g, ushort* l) {
  __builtin_amdgcn_global_load_lds(
      (const __attribute__((address_space(1))) unsigned int*)g,
      (__attribute__((address_space(3))) unsigned int*)l, 16, 0, 0);
}
#else
__device__ __forceinline__ void gload16(const ushort* g, ushort* l) {
  const int lane = __builtin_amdgcn_mbcnt_hi(~0u, __builtin_amdgcn_mbcnt_lo(~0u, 0));
  *reinterpret_cast<uint4*>((char*)l + lane * 16) = *reinterpret_cast<const uint4*>(g);
}
#endif

// ---------------------------------------------------------------------------
// Precompute pass: casts (f32 -> bf16) and the Wo split.
// ---------------------------------------------------------------------------
__device__ __forceinline__ void cast_octet(const float* __restrict__ src,
                                           ushort* __restrict__ dst, int o) {
  const float4 f0 = *reinterpret_cast<const float4*>(src + (size_t)o * 8);
  const float4 f1 = *reinterpret_cast<const float4*>(src + (size_t)o * 8 + 4);
  uint4 u;
  u.x = (unsigned int)f2bf(f0.x) | ((unsigned int)f2bf(f0.y) << 16);
  u.y = (unsigned int)f2bf(f0.z) | ((unsigned int)f2bf(f0.w) << 16);
  u.z = (unsigned int)f2bf(f1.x) | ((unsigned int)f2bf(f1.y) << 16);
  u.w = (unsigned int)f2bf(f1.z) | ((unsigned int)f2bf(f1.w) << 16);
  *reinterpret_cast<uint4*>(dst + (size_t)o * 8) = u;
}

__device__ __forceinline__ void split_octet(const float* __restrict__ src,
                                            ushort* __restrict__ dst, int o) {
  const float4 f0 = *reinterpret_cast<const float4*>(src + (size_t)o * 8);
  const float4 f1 = *reinterpret_cast<const float4*>(src + (size_t)o * 8 + 4);
  float xs[8] = {f0.x, f0.y, f0.z, f0.w, f1.x, f1.y, f1.z, f1.w};
  unsigned int hp[4], lp[4];
#pragma unroll
  for (int j = 0; j < 4; ++j) {
    const unsigned int u0 = __float_as_uint(xs[2 * j]);
    const unsigned int u1 = __float_as_uint(xs[2 * j + 1]);
    const unsigned int h0 = u0 & 0xffff0000u;
    const unsigned int h1 = u1 & 0xffff0000u;
    hp[j] = (h0 >> 16) | h1;
    const float r0 = xs[2 * j] - __uint_as_float(h0);
    const float r1 = xs[2 * j + 1] - __uint_as_float(h1);
    lp[j] = (__float_as_uint(r0) >> 16) | (__float_as_uint(r1) & 0xffff0000u);
  }
  uint4* d = reinterpret_cast<uint4*>(dst + (size_t)o * 16);
  d[0] = make_uint4(hp[0], hp[1], hp[2], hp[3]);
  d[1] = make_uint4(lp[0], lp[1], lp[2], lp[3]);
}

// y = 0..2: cast q,k,v; y = 3..5: cast Wq,Wk,Wv; y = 6: split Wo.
__global__ __launch_bounds__(256)
void cast_split(const float* __restrict__ q, const float* __restrict__ k,
                const float* __restrict__ v, const float* __restrict__ Wq,
                const float* __restrict__ Wk, const float* __restrict__ Wv,
                const float* __restrict__ Wo,
                ushort* __restrict__ qB, ushort* __restrict__ kB,
                ushort* __restrict__ vB, ushort* __restrict__ WqB,
                ushort* __restrict__ WkB, ushort* __restrict__ WvB,
                ushort* __restrict__ WoS) {
  const int o = blockIdx.x * 256 + threadIdx.x;
  constexpr int NA = NTOK * Dv / 8;  // 524288
  constexpr int NW = Dv * Dv / 8;    // 131072
  switch (blockIdx.y) {
    case 0: if (o < NA) cast_octet(q, qB, o); break;
    case 1: if (o < NA) cast_octet(k, kB, o); break;
    case 2: if (o < NA) cast_octet(v, vB, o); break;
    case 3: if (o < NW) cast_octet(Wq, WqB, o); break;
    case 4: if (o < NW) cast_octet(Wk, WkB, o); break;
    case 5: if (o < NW) cast_octet(Wv, WvB, o); break;
    default: if (o < NW) split_octet(Wo, WoS, o); break;
  }
}

// ---------------------------------------------------------------------------
// Plain bf16 MFMA GEMM for Q/K/V projections (verified r7/r8: error-neutral).
// Staging via global_load_lds w=16: linear LDS dest, PRE-SWIZZLED global
// source (rule 21) so the swizzled read path is unchanged.
// ---------------------------------------------------------------------------
__global__ __launch_bounds__(256, 2)
void gemm_qkv_bf16(const ushort* __restrict__ qB, const ushort* __restrict__ kB,
                   const ushort* __restrict__ vB,
                   const ushort* __restrict__ WqB, const ushort* __restrict__ WkB,
                   const ushort* __restrict__ WvB,
                   ushort* __restrict__ Qw, ushort* __restrict__ Kw,
                   ushort* __restrict__ Vw) {
  // bijective XCD swizzle: nwg = 768 = 8*96
  const int hid = (int)blockIdx.z * 256 + (int)blockIdx.y * 8 + (int)blockIdx.x;
  const int id  = (hid & 7) * 96 + (hid >> 3);
  const int bn = id & 7;
  const int bm = (id >> 3) & 31;
  const int bz = id >> 8;

  const ushort* Ag;
  const ushort* Wg;
  ushort* Y;
  float scale = 1.0f;
  if (bz == 0)      { Ag = qB; Wg = WqB; Y = Qw; scale = QSCALE; }
  else if (bz == 1) { Ag = kB; Wg = WkB; Y = Kw; }
  else              { Ag = vB; Wg = WvB; Y = Vw; }

  __shared__ __align__(16) ushort AT[128 * 128];
  __shared__ __align__(16) ushort WT[128 * 128];

  const int tid  = threadIdx.x;
  const int lane = tid & 63;
  const int wv   = tid >> 6;
  const int wr = wv >> 1, wc = wv & 1;
  const int c = lane & 15, g = lane >> 4;

  f32x4 acc[4][4];
#pragma unroll
  for (int m = 0; m < 4; ++m)
#pragma unroll
    for (int n = 0; n < 4; ++n) acc[m][n] = (f32x4){0.f, 0.f, 0.f, 0.f};

  // staging: wave wv, chunk it covers LDS [it*4096 + wv*1024, +1024).
  // LDS byte L = it*4096 + wv*1024 + lane*16 -> row = it*16+wv*4+(lane>>4),
  // linear slot = lane&15; data there must be global slot (lane&15)^(row&7).
  const ushort* aS[8];
  const ushort* wS[8];
  ushort* aD[8];
  ushort* wD[8];
#pragma unroll
  for (int it = 0; it < 8; ++it) {
    const int row  = it * 16 + wv * 4 + (lane >> 4);
    const int slot = (lane & 15) ^ (row & 7);
    aS[it] = Ag + (size_t)(bm * 128 + row) * 1024 + slot * 8;
    wS[it] = Wg + (size_t)(bn * 128 + row) * 1024 + slot * 8;
    aD[it] = (ushort*)((char*)AT + it * 4096 + wv * 1024);
    wD[it] = (ushort*)((char*)WT + it * 4096 + wv * 1024);
  }

  for (int kt = 0; kt < 8; ++kt) {  // BK = 128
    __syncthreads();
#pragma unroll
    for (int it = 0; it < 8; ++it) gload16(aS[it] + kt * 128, aD[it]);
#pragma unroll
    for (int it = 0; it < 8; ++it) gload16(wS[it] + kt * 128, wD[it]);
    __syncthreads();  // compiler drains vmcnt before barrier

#pragma unroll
    for (int kk = 0; kk < 4; ++kk) {
      const int ob = kk * 64 + 16 * g;
      bf16x8 bh[4];
#pragma unroll
      for (int n = 0; n < 4; ++n) {
        const int row = wc * 64 + n * 16 + c;
        bh[n] = *reinterpret_cast<const bf16x8*>((const char*)WT + swz(row * 256 + ob, row));
      }
#pragma unroll
      for (int m = 0; m < 4; ++m) {
        const int row = wr * 64 + m * 16 + c;
        const bf16x8 ah = *reinterpret_cast<const bf16x8*>((const char*)AT + swz(row * 256 + ob, row));
#pragma unroll
        for (int n = 0; n < 4; ++n)
          acc[m][n] = __builtin_amdgcn_mfma_f32_16x16x32_bf16(ah, bh[n], acc[m][n], 0, 0, 0);
      }
    }
  }

#pragma unroll
  for (int m = 0; m < 4; ++m)
#pragma unroll
    for (int n = 0; n < 4; ++n)
#pragma unroll
      for (int r = 0; r < 4; ++r) {
        const int tok = bm * 128 + wr * 64 + m * 16 + 4 * g + r;
        const int e   = bn * 128 + wc * 64 + n * 16 + c;
        const int bb = tok >> 11, ss = tok & (Sv - 1);
        const int hh = e >> 6, dk = e & (DKv - 1);
        Y[(((size_t)bb * Hv + hh) * Sv + ss) * DKv + dk] = f2bf(acc[m][n][r] * scale);
      }
}

// ---------------------------------------------------------------------------
// 3-term split-precision bf16 MFMA GEMM for the OUTPUT projection
// (fp32-grade; verified rounds 5-8). Same gload_lds staging.
// ---------------------------------------------------------------------------
__global__ __launch_bounds__(256, 2)
void gemm_out_mfma(const ushort* __restrict__ Ag, const ushort* __restrict__ Wg,
                   float* __restrict__ out) {
  const int hid = (int)blockIdx.y * 8 + (int)blockIdx.x;
  const int id  = (hid & 7) * 32 + (hid >> 3);
  const int bn = id & 7;
  const int bm = id >> 3;

  __shared__ __align__(16) ushort AT[128 * 128];
  __shared__ __align__(16) ushort WT[128 * 128];

  const int tid  = threadIdx.x;
  const int lane = tid & 63;
  const int wv   = tid >> 6;
  const int wr = wv >> 1, wc = wv & 1;
  const int c = lane & 15, g = lane >> 4;

  f32x4 acc[4][4];
#pragma unroll
  for (int m = 0; m < 4; ++m)
#pragma unroll
    for (int n = 0; n < 4; ++n) acc[m][n] = (f32x4){0.f, 0.f, 0.f, 0.f};

  const ushort* aS[8];
  const ushort* wS[8];
  ushort* aD[8];
  ushort* wD[8];
#pragma unroll
  for (int it = 0; it < 8; ++it) {
    const int row  = it * 16 + wv * 4 + (lane >> 4);
    const int slot = (lane & 15) ^ (row & 7);
    aS[it] = Ag + (size_t)(bm * 128 + row) * 2048 + slot * 8;
    wS[it] = Wg + (size_t)(bn * 128 + row) * 2048 + slot * 8;
    aD[it] = (ushort*)((char*)AT + it * 4096 + wv * 1024);
    wD[it] = (ushort*)((char*)WT + it * 4096 + wv * 1024);
  }

  for (int kt = 0; kt < 16; ++kt) {
    __syncthreads();
#pragma unroll
    for (int it = 0; it < 8; ++it) gload16(aS[it] + kt * 128, aD[it]);
#pragma unroll
    for (int it = 0; it < 8; ++it) gload16(wS[it] + kt * 128, wD[it]);
    __syncthreads();

#pragma unroll
    for (int kk = 0; kk < 2; ++kk) {
      const int ob = (kk * 4 + g) * 32;
      bf16x8 bh[4], bl[4];
#pragma unroll
      for (int n = 0; n < 4; ++n) {
        const int row = wc * 64 + n * 16 + c;
        const char* p = (const char*)WT;
        bh[n] = *reinterpret_cast<const bf16x8*>(p + swz(row * 256 + ob, row));
        bl[n] = *reinterpret_cast<const bf16x8*>(p + swz(row * 256 + ob + 16, row));
      }
#pragma unroll
      for (int m = 0; m < 4; ++m) {
        const int row = wr * 64 + m * 16 + c;
        const char* p = (const char*)AT;
        const bf16x8 ah = *reinterpret_cast<const bf16x8*>(p + swz(row * 256 + ob, row));
        const bf16x8 al = *reinterpret_cast<const bf16x8*>(p + swz(row * 256 + ob + 16, row));
#pragma unroll
        for (int n = 0; n < 4; ++n) {
          acc[m][n] = __builtin_amdgcn_mfma_f32_16x16x32_bf16(ah, bh[n], acc[m][n], 0, 0, 0);
          acc[m][n] = __builtin_amdgcn_mfma_f32_16x16x32_bf16(al, bh[n], acc[m][n], 0, 0, 0);
          acc[m][n] = __builtin_amdgcn_mfma_f32_16x16x32_bf16(ah, bl[n], acc[m][n], 0, 0, 0);
        }
      }
    }
  }

#pragma unroll
  for (int m = 0; m < 4; ++m)
#pragma unroll
    for (int n = 0; n < 4; ++n)
#pragma unroll
      for (int r = 0; r < 4; ++r) {
        const int tok = bm * 128 + wr * 64 + m * 16 + 4 * g + r;
        const int e   = bn * 128 + wc * 64 + n * 16 + c;
        out[(size_t)tok * Dv + e] = acc[m][n][r];
      }
}

// ---------------------------------------------------------------------------
// Causal flash attention, bf16 MFMA, double-buffered + reg-prefetch.
// v3: 512 blocks x 4 waves (256 thr), 64-row half-tiles. Block x processes
// half-items x and 1023-x of the qh-sorted list (qh_a + qh_b = 31 -> every
// block = exactly 34 KV iterations) -> 2 blocks/CU (16 waves/CU, double r8).
// VALU diet: P-pack via v_cvt_pk_bf16_f32 + ds_write_b64; T13 defer-max
// (THR=8 in exp2 domain) skips rescale when the running max barely grows.
// LDS 40KB: K dbuf 2x8K | V dbuf 2x8K | P 4x2K; Q overlays K buf0.
// ---------------------------------------------------------------------------
__global__ __launch_bounds__(256)
void attn_fwd_mfma(const ushort* __restrict__ Q, const ushort* __restrict__ K,
                   const ushort* __restrict__ V, ushort* __restrict__ XS) {
  const int tid  = threadIdx.x;
  const int lane = tid & 63;
  const int w    = tid >> 6;        // wave 0..3
  const int c    = lane & 15;
  const int g    = lane >> 4;

  __shared__ __align__(16) char lds[40960];
  // K buf i: lds + i*8192; V buf i: lds + 16384 + i*8192; P: lds + 32768 + w*2048

  // staging address components (fixed across items)
  const int kr_s = tid >> 2;             // K row 0..63
  const int kcb  = (tid & 3) << 5;       // K byte col 0,32,64,96 (2 x 16B)
  const int vi_s = tid & 31;             // V row pair 0..31
  const int vc_s = (tid >> 5) << 3;      // V dk col 0,8,..,56

#pragma unroll 1
  for (int item = 0; item < 2; ++item) {
    const int hx = (item == 0) ? (int)blockIdx.x : 1023 - (int)blockIdx.x;
    const int qh = hx >> 5;        // 64-row q half-tile index 0..31
    const int bh = hx & 31;
    const int b = bh >> 4, h = bh & (Hv - 1);
    const int qtk = qh;            // last KV tile index

    const ushort* Qb = Q + (size_t)bh * Sv * DKv;
    const ushort* Kb = K + (size_t)bh * Sv * DKv;
    const ushort* Vb = V + (size_t)bh * Sv * DKv;

    // ---- stage Q (64 rows x 128B) into K buf0 region ----
    {
      const int r  = tid >> 2;             // 0..63
      const int c0 = (tid & 3) << 4;       // bf16 col
      const ushort* src = Qb + (size_t)(qh * 64 + r) * DKv + c0;
      uint4 v0 = *reinterpret_cast<const uint4*>(src);
      uint4 v1 = *reinterpret_cast<const uint4*>(src + 8);
      *reinterpret_cast<uint4*>(lds + swz(r * 128 + 2 * c0, r))      = v0;
      *reinterpret_cast<uint4*>(lds + swz(r * 128 + 2 * c0 + 16, r)) = v1;
    }
    __syncthreads();

    // ---- Q frags (B-operand), wave w owns q-rows w*16..w*16+15 ----
    bf16x8 qf0, qf1;
    {
      const int qr = w * 16 + c;
      qf0 = *reinterpret_cast<const bf16x8*>(lds + swz(qr * 128 + 16 * g, qr));
      qf1 = *reinterpret_cast<const bf16x8*>(lds + swz(qr * 128 + 64 + 16 * g, qr));
    }

    uint4 kA0, kA1, vA, vB;
    kA0 = *reinterpret_cast<const uint4*>((const char*)Kb + (size_t)kr_s * 128 + kcb);
    kA1 = *reinterpret_cast<const uint4*>((const char*)Kb + (size_t)kr_s * 128 + kcb + 16);
    {
      const ushort* vs = Vb + (size_t)(2 * vi_s) * DKv + vc_s;
      vA = *reinterpret_cast<const uint4*>(vs);
      vB = *reinterpret_cast<const uint4*>(vs + DKv);
    }
    __syncthreads();  // all waves done reading Q region before K write

    // ---- write tile 0 into buf 0 ----
    *reinterpret_cast<uint4*>(lds + swz(kr_s * 128 + kcb, kr_s))      = kA0;
    *reinterpret_cast<uint4*>(lds + swz(kr_s * 128 + kcb + 16, kr_s)) = kA1;
    {
      char* vd = lds + 16384;
      unsigned int ee[4] = {vA.x, vA.y, vA.z, vA.w};
      unsigned int oo[4] = {vB.x, vB.y, vB.z, vB.w};
#pragma unroll
      for (int p = 0; p < 4; ++p) {
        unsigned int lo = (ee[p] & 0xffffu) | (oo[p] << 16);
        unsigned int hi = (ee[p] >> 16) | (oo[p] & 0xffff0000u);
        const int d0 = vc_s + 2 * p;
        *reinterpret_cast<unsigned int*>(vd + swz(d0 * 128 + 4 * vi_s, d0))           = lo;
        *reinterpret_cast<unsigned int*>(vd + swz((d0 + 1) * 128 + 4 * vi_s, d0 + 1)) = hi;
      }
    }
    __syncthreads();

    f32x4 accO[4];
#pragma unroll
    for (int ds = 0; ds < 4; ++ds) accO[ds] = (f32x4){0.f, 0.f, 0.f, 0.f};
    float mS = -3.0e38f, lS = 0.f;

    for (int kv = 0; kv <= qtk; ++kv) {
      const int cur = kv & 1;

      // ---- issue next tile's global loads (in flight during compute) ----
      if (kv < qtk) {
        const char* ks = (const char*)Kb + ((size_t)(kv + 1) * 64 + kr_s) * 128;
        kA0 = *reinterpret_cast<const uint4*>(ks + kcb);
        kA1 = *reinterpret_cast<const uint4*>(ks + kcb + 16);
        const ushort* vs = Vb + (size_t)((kv + 1) * 64 + 2 * vi_s) * DKv + vc_s;
        vA = *reinterpret_cast<const uint4*>(vs);
        vB = *reinterpret_cast<const uint4*>(vs + DKv);
      }

      const char* kbase = lds + cur * 8192;
      const char* vbase = lds + 16384 + cur * 8192;
      char* pbase = lds + 32768 + w * 2048;

      // ---- QK^T (swapped): lane owns q = w*16+c, key = kv*64 + kt*16+4g+rr ----
      f32x4 s[4];
#pragma unroll
      for (int kt = 0; kt < 4; ++kt) {
        const int kr = kt * 16 + c;
        bf16x8 kf0 = *reinterpret_cast<const bf16x8*>(kbase + swz(kr * 128 + 16 * g, kr));
        bf16x8 kf1 = *reinterpret_cast<const bf16x8*>(kbase + swz(kr * 128 + 64 + 16 * g, kr));
        f32x4 z = (f32x4){0.f, 0.f, 0.f, 0.f};
        z = __builtin_amdgcn_mfma_f32_16x16x32_bf16(kf0, qf0, z, 0, 0, 0);
        s[kt] = __builtin_amdgcn_mfma_f32_16x16x32_bf16(kf1, qf1, z, 0, 0, 0);
      }

      // ---- causal mask (diagonal tile only) ----
      if (kv == qtk) {
        const int ql = w * 16 + c;   // row within half-tile; key tile aligned
#pragma unroll
        for (int kt = 0; kt < 4; ++kt)
#pragma unroll
          for (int rr = 0; rr < 4; ++rr) {
            const int kl = kt * 16 + 4 * g + rr;
            if (kl > ql) s[kt][rr] = -3.0e38f;
          }
      }

      // ---- online softmax (exp2 domain) with T13 defer-max ----
      float tm = -3.0e38f;
#pragma unroll
      for (int kt = 0; kt < 4; ++kt)
#pragma unroll
        for (int rr = 0; rr < 4; ++rr) tm = fmaxf(tm, s[kt][rr]);
      tm = fmaxf(tm, __shfl_xor(tm, 16));
      tm = fmaxf(tm, __shfl_xor(tm, 32));

      const bool noresc = (__all(tm - mS <= 8.0f) != 0);  // wave-uniform
      float corr = 1.0f;
      if (!noresc) {
        const float mnew = fmaxf(mS, tm);
        corr = fast_exp2(mS - mnew);
        mS = mnew;
      }

      float psum = 0.f;
#pragma unroll
      for (int kt = 0; kt < 4; ++kt)
#pragma unroll
        for (int rr = 0; rr < 4; ++rr) {
          const float p = fast_exp2(s[kt][rr] - mS);
          s[kt][rr] = p;
          psum += p;
        }
      psum += __shfl_xor(psum, 16);
      psum += __shfl_xor(psum, 32);
      lS = lS * corr + psum;

      // ---- P -> wave-private LDS (cvt_pk bf16 pairs, one b64 per kt) ----
#pragma unroll
      for (int kt = 0; kt < 4; ++kt) {
        unsigned int lo, hi;
        asm("v_cvt_pk_bf16_f32 %0, %1, %2" : "=v"(lo) : "v"(s[kt][0]), "v"(s[kt][1]));
        asm("v_cvt_pk_bf16_f32 %0, %1, %2" : "=v"(hi) : "v"(s[kt][2]), "v"(s[kt][3]));
        *reinterpret_cast<uint2*>(pbase + swz(c * 128 + kt * 32 + 8 * g, c)) =
            make_uint2(lo, hi);
      }

      // ---- rescale accO (skipped on deferred tiles) ----
      if (!noresc) {
        float corr4[4];
#pragma unroll
        for (int rr = 0; rr < 4; ++rr)
          corr4[rr] = __int_as_float(__builtin_amdgcn_ds_bpermute(
              (4 * g + rr) << 2, __float_as_int(corr)));
#pragma unroll
        for (int ds = 0; ds < 4; ++ds)
#pragma unroll
          for (int rr = 0; rr < 4; ++rr) accO[ds][rr] *= corr4[rr];
      }

      // ---- PV ----
#pragma unroll
      for (int ks = 0; ks < 2; ++ks) {
        bf16x8 pf = *reinterpret_cast<const bf16x8*>(pbase + swz(c * 128 + ks * 64 + 16 * g, c));
#pragma unroll
        for (int ds = 0; ds < 4; ++ds) {
          const int dk = ds * 16 + c;
          bf16x8 vf = *reinterpret_cast<const bf16x8*>(vbase + swz(dk * 128 + ks * 64 + 16 * g, dk));
          accO[ds] = __builtin_amdgcn_mfma_f32_16x16x32_bf16(pf, vf, accO[ds], 0, 0, 0);
        }
      }

      // ---- write next tile into alternate buffer (safe: one barrier/iter) ----
      if (kv < qtk) {
        char* kd = lds + (cur ^ 1) * 8192;
        *reinterpret_cast<uint4*>(kd + swz(kr_s * 128 + kcb, kr_s))      = kA0;
        *reinterpret_cast<uint4*>(kd + swz(kr_s * 128 + kcb + 16, kr_s)) = kA1;
        char* vd = lds + 16384 + (cur ^ 1) * 8192;
        unsigned int ee[4] = {vA.x, vA.y, vA.z, vA.w};
        unsigned int oo[4] = {vB.x, vB.y, vB.z, vB.w};
#pragma unroll
        for (int p = 0; p < 4; ++p) {
          unsigned int lo = (ee[p] & 0xffffu) | (oo[p] << 16);
          unsigned int hi = (ee[p] >> 16) | (oo[p] & 0xffff0000u);
          const int d0 = vc_s + 2 * p;
          *reinterpret_cast<unsigned int*>(vd + swz(d0 * 128 + 4 * vi_s, d0))           = lo;
          *reinterpret_cast<unsigned int*>(vd + swz((d0 + 1) * 128 + 4 * vi_s, d0 + 1)) = hi;
        }
      }
      __syncthreads();
    }

    // ---- epilogue: write X directly in split hi/lo octet layout ----
    {
      const float inv = 1.0f / lS;
      float inv4[4];
#pragma unroll
      for (int rr = 0; rr < 4; ++rr)
        inv4[rr] = __int_as_float(__builtin_amdgcn_ds_bpermute(
            (4 * g + rr) << 2, __float_as_int(inv)));
      const int q0 = qh * 64 + w * 16;
#pragma unroll
      for (int ds = 0; ds < 4; ++ds) {
        const int e   = h * DKv + ds * 16 + c;
        const int oct = e >> 3, j = e & 7;
#pragma unroll
        for (int rr = 0; rr < 4; ++rr) {
          const int srow = q0 + 4 * g + rr;
          const float y = accO[ds][rr] * inv4[rr];
          const unsigned int u  = __float_as_uint(y);
          const unsigned int hb = u & 0xffff0000u;
          const float rlo = y - __uint_as_float(hb);
          ushort* d = XS + ((size_t)(b * Sv + srow)) * 2048 + oct * 16 + j;
          d[0] = (ushort)(u >> 16);
          d[8] = (ushort)(__float_as_uint(rlo) >> 16);
        }
      }
    }
    if (item == 0) __syncthreads();  // LDS reuse safety before next item
  }
}

// ---------------------------------------------------------------------------
// launch
// ---------------------------------------------------------------------------
extern "C" void kernel_launch(void* const* d_in, const int* in_sizes, int n_in,
                              void* d_out, int out_size, void* d_ws, size_t ws_size,
                              hipStream_t stream) {
  const float* q  = (const float*)d_in[0];
  const float* k  = (const float*)d_in[1];
  const float* v  = (const float*)d_in[2];
  // d_in[3] = mask: causal tril, handled analytically
  const float* Wq = (const float*)d_in[4];
  const float* Wk = (const float*)d_in[5];
  const float* Wv = (const float*)d_in[6];
  const float* Wo = (const float*)d_in[7];
  float* out = (float*)d_out;

  constexpr size_t SEG   = (size_t)NTOK * Dv;
  constexpr size_t ACT_S = SEG * 2;               // bf16 act buffer
  constexpr size_t X_S   = SEG * 4;               // (spare)
  constexpr size_t WB_S  = (size_t)Dv * Dv * 2;   // bf16 weight
  constexpr size_t SPW_S = (size_t)Dv * Dv * 4;   // split Wo

  char* ws = (char*)d_ws;
  ushort* Qw  = (ushort*)(ws);
  ushort* Kw  = (ushort*)(ws + ACT_S);
  ushort* Vw  = (ushort*)(ws + 2 * ACT_S);
  ushort* qB  = (ushort*)(ws + 3 * ACT_S + X_S);
  ushort* kB  = (ushort*)(ws + 3 * ACT_S + X_S + ACT_S);
  ushort* vB  = (ushort*)(ws + 3 * ACT_S + X_S + 2 * ACT_S);
  ushort* WqB = (ushort*)(ws + 3 * ACT_S + X_S + 3 * ACT_S);
  ushort* WkB = (ushort*)(ws + 3 * ACT_S + X_S + 3 * ACT_S + WB_S);
  ushort* WvB = (ushort*)(ws + 3 * ACT_S + X_S + 3 * ACT_S + 2 * WB_S);
  ushort* WoS = (ushort*)(ws + 3 * ACT_S + X_S + 3 * ACT_S + 3 * WB_S);
  ushort* XS  = (ushort*)(ws + 3 * ACT_S + X_S + 3 * ACT_S + 3 * WB_S + SPW_S);

  const dim3 blk(256);
  cast_split<<<dim3(NTOK * Dv / 8 / 256, 7), blk, 0, stream>>>(
      q, k, v, Wq, Wk, Wv, Wo, qB, kB, vB, WqB, WkB, WvB, WoS);
  gemm_qkv_bf16<<<dim3(8, 32, 3), blk, 0, stream>>>(
      qB, kB, vB, WqB, WkB, WvB, Qw, Kw, Vw);
  attn_fwd_mfma<<<dim3(512), blk, 0, stream>>>(Qw, Kw, Vw, XS);
  gemm_out_mfma<<<dim3(8, 32), blk, 0, stream>>>(XS, WoS, out);
}